// Round 4
// baseline (9502.663 us; speedup 1.0000x reference)
//
#include <hip/hip_runtime.h>
#include <math.h>

#define NB 16
#define NE 4
#define THRESH 0.2f

// ---------------- repack kernels ----------------
// ew layout: ((e*CO + co)*C + c)*9 + ij  ->  w3: ((c*9 + ij)*CO + co)*NE + e
// so a wave's 16-co x 4-e slice per (c,ij) is 64 contiguous floats.
__global__ void repack_w_kernel(const float* __restrict__ ew, float* __restrict__ w3,
                                int CO, int C) {
    int n = NE * CO * C * 9;
    for (int i = blockIdx.x * blockDim.x + threadIdx.x; i < n; i += gridDim.x * blockDim.x) {
        int ij = i % 9;
        int t = i / 9;
        int c = t % C; t /= C;
        int co = t % CO;
        int e = t / CO;
        w3[((size_t)(c * 9 + ij) * CO + co) * NE + e] = ew[i];
    }
}

// fwT[c*Co + o] = fw[o*Co + c]
__global__ void repack_fin_kernel(const float* __restrict__ fw, float* __restrict__ fwT, int Co) {
    int n = Co * Co;
    for (int i = blockIdx.x * blockDim.x + threadIdx.x; i < n; i += gridDim.x * blockDim.x) {
        int o = i / Co, c = i % Co;
        fwT[c * Co + o] = fw[i];
    }
}

// ---------------- router: pooled conv -> softmax scores ----------------
template<int CIN, int C>
__global__ __launch_bounds__(256) void router_kernel(
    const float* __restrict__ X, const float* __restrict__ pw, const float* __restrict__ pb,
    const float* __restrict__ rw, const float* __restrict__ rb,
    float* __restrict__ scores, int H, int W, int nP)
{
    __shared__ float S[4][C * 9 + 8];
    const int wv = threadIdx.x >> 6;
    const int lane = threadIdx.x & 63;
    const int bp = blockIdx.x * 4 + wv;
    const int P = nP * nP;
    const int b = bp / P, pi = bp % P;
    const int py = pi / nP, px = pi % nP;
    const int h = lane >> 3, w = lane & 7;
    const int gy = py * 8 + h, gx = px * 8 + w;
    float* Sw = S[wv];
    for (int c = 0; c < C; ++c) {
        float v;
        if (c < CIN) {
            v = X[(((size_t)b * CIN + c) * H + gy) * W + gx];
        } else {
            float t = (c == CIN || c == CIN + 2) ? gx * (1.f / (W - 1)) : gy * (1.f / (H - 1));
            v = (c >= CIN + 2) ? sinf(3.14159265358979323846f * t) : t;
        }
        float r = v;                       // row sums: lanes grouped by h (8 consecutive)
        r += __shfl_xor(r, 1); r += __shfl_xor(r, 2); r += __shfl_xor(r, 4);
        float cc = v;                      // col sums: lanes grouped by w
        cc += __shfl_xor(cc, 8); cc += __shfl_xor(cc, 16); cc += __shfl_xor(cc, 32);
        float T = r;
        T += __shfl_xor(T, 8); T += __shfl_xor(T, 16); T += __shfl_xor(T, 32);
        float R0 = __shfl(r, 0), R7 = __shfl(r, 56);
        float C0 = __shfl(cc, 0), C7 = __shfl(cc, 7);
        float x00 = __shfl(v, 0), x07 = __shfl(v, 7);
        float x70 = __shfl(v, 56), x77 = __shfl(v, 63);
        if (lane < 9) {
            int i = lane / 3, j = lane % 3;
            float s = T;
            if (i == 0) s -= R7; else if (i == 2) s -= R0;
            if (j == 0) s -= C7; else if (j == 2) s -= C0;
            if (i == 0 && j == 0) s += x77;
            else if (i == 0 && j == 2) s += x70;
            else if (i == 2 && j == 0) s += x07;
            else if (i == 2 && j == 2) s += x00;
            Sw[c * 9 + lane] = s;
        }
    }
    __syncthreads();
    if (lane < 8) {
        const int o = lane;
        float acc = 0.f;
        for (int c = 0; c < C; ++c) {
            #pragma unroll
            for (int ij = 0; ij < 9; ++ij)
                acc += pw[(o * C + c) * 9 + ij] * Sw[c * 9 + ij];
        }
        Sw[C * 9 + o] = acc * (1.f / 64.f) + pb[o];
    }
    __syncthreads();
    if (lane == 0) {
        float lg[NE];
        float m = -1e30f;
        #pragma unroll
        for (int e = 0; e < NE; ++e) {
            float a = rb[e];
            #pragma unroll
            for (int o = 0; o < 8; ++o) a += Sw[C * 9 + o] * rw[e * 8 + o];
            lg[e] = a;
            m = fmaxf(m, a);
        }
        float ssum = 0.f;
        #pragma unroll
        for (int e = 0; e < NE; ++e) { lg[e] = __expf(lg[e] - m); ssum += lg[e]; }
        float inv = 1.f / ssum;
        #pragma unroll
        for (int e = 0; e < NE; ++e) scores[bp * NE + e] = lg[e] * inv;
    }
}

// ---------------- gate: per-expert global max > THRESH ----------------
__global__ __launch_bounds__(256) void gate_kernel(const float* __restrict__ scores, int BP,
                                                   float* __restrict__ gate)
{
    __shared__ float sm[4][NE];
    float m[NE] = {-1e30f, -1e30f, -1e30f, -1e30f};
    for (int i = threadIdx.x; i < BP; i += 256) {
        #pragma unroll
        for (int e = 0; e < NE; ++e) m[e] = fmaxf(m[e], scores[i * NE + e]);
    }
    #pragma unroll
    for (int e = 0; e < NE; ++e) {
        float v = m[e];
        for (int o = 32; o; o >>= 1) v = fmaxf(v, __shfl_xor(v, o));
        m[e] = v;
    }
    int wv = threadIdx.x >> 6, lane = threadIdx.x & 63;
    if (lane == 0) {
        #pragma unroll
        for (int e = 0; e < NE; ++e) sm[wv][e] = m[e];
    }
    __syncthreads();
    if (threadIdx.x == 0) {
        #pragma unroll
        for (int e = 0; e < NE; ++e) {
            float mx = fmaxf(fmaxf(sm[0][e], sm[1][e]), fmaxf(sm[2][e], sm[3][e]));
            gate[e] = (mx > THRESH) ? 1.f : 0.f;
        }
    }
}

// ---------------- expert conv + relu + gated combine -> img ----------------
// one block per patch; padded patch in LDS; wave wv owns a CPW co-range, processed
// in tiles of 16 co x 4 experts (64 accumulators). Per (c,ij) the wave's weights
// are 64 CONTIGUOUS floats (repacked [c][ij][co][e]) -> s_load_dwordx16 friendly.
// __launch_bounds__(256,3): cap allocator at ~170 VGPR so the 64 accumulators
// stay in registers (round-3 spill: VGPR_Count 44 with scratch, 41.8ms dispatch).
template<int CIN, int C, int CO>
__global__ __launch_bounds__(256, 3) void expert_kernel(
    const float* __restrict__ X, const float* __restrict__ w3, const float* __restrict__ eb,
    const float* __restrict__ scores, const float* __restrict__ gate,
    float* __restrict__ img, int H, int W, int nP)
{
    __shared__ float pat[C * 100];  // C x 10 x 10, zero border
    const int P = nP * nP;
    const int bp = blockIdx.x;
    const int b = bp / P, pi = bp % P;
    const int py = pi / nP, px = pi % nP;
    const int tid = threadIdx.x;

    for (int i = tid; i < C * 100; i += 256) pat[i] = 0.f;
    __syncthreads();
    for (int i = tid; i < C * 64; i += 256) {
        int c = i >> 6, p = i & 63, h = p >> 3, w = p & 7;
        int gy = py * 8 + h, gx = px * 8 + w;
        float v;
        if (c < CIN) {
            v = X[(((size_t)b * CIN + c) * H + gy) * W + gx];
        } else {
            float t = (c == CIN || c == CIN + 2) ? gx * (1.f / (W - 1)) : gy * (1.f / (H - 1));
            v = (c >= CIN + 2) ? sinf(3.14159265358979323846f * t) : t;
        }
        pat[c * 100 + (h + 1) * 10 + (w + 1)] = v;
    }
    __syncthreads();

    float sg[NE];
    #pragma unroll
    for (int e = 0; e < NE; ++e) sg[e] = scores[bp * NE + e] * gate[e];

    const int pix = tid & 63, h = pix >> 3, w = pix & 7, wv = tid >> 6;
    const int y = py * 8 + h, x = px * 8 + w;
    const int CPW = CO / 4;           // co per wave (16 or 32)
    const int base = h * 10 + w;      // tap (i,j) at base + i*10 + j in a 10x10 plane

    for (int co_t = 0; co_t < CPW; co_t += 16) {
        const int co0 = __builtin_amdgcn_readfirstlane(wv * CPW + co_t);
        float acc[NE][16];
        #pragma unroll
        for (int e = 0; e < NE; ++e)
            #pragma unroll
            for (int k = 0; k < 16; ++k) acc[e][k] = eb[e * CO + co0 + k];

        const float* wbase = w3 + (size_t)co0 * NE;
        for (int c = 0; c < C; ++c) {
            float n[9];
            #pragma unroll
            for (int i = 0; i < 3; ++i)
                #pragma unroll
                for (int j = 0; j < 3; ++j) n[i * 3 + j] = pat[c * 100 + base + i * 10 + j];
            const float* wcc = wbase + (size_t)(c * 9) * CO * NE;
            #pragma unroll
            for (int ij = 0; ij < 9; ++ij) {
                const float nv = n[ij];
                const float* wr = wcc + (size_t)ij * CO * NE;   // 64 contiguous floats
                #pragma unroll
                for (int k = 0; k < 16; ++k)
                    #pragma unroll
                    for (int e = 0; e < NE; ++e)
                        acc[e][k] = fmaf(wr[k * NE + e], nv, acc[e][k]);
            }
        }
        #pragma unroll
        for (int k = 0; k < 16; ++k) {
            float cv = 0.f;
            #pragma unroll
            for (int e = 0; e < NE; ++e) cv += sg[e] * fmaxf(acc[e][k], 0.f);
            img[(((size_t)b * CO + co0 + k) * H + y) * W + x] = cv;
        }
    }
}

// ---------------- fin: 1x1 conv with pad 4 (border = bias) ----------------
__global__ __launch_bounds__(128) void fin_kernel(
    const float* __restrict__ img, const float* __restrict__ fwT, const float* __restrict__ fb,
    float* __restrict__ Xn, int Co, int H, int W)
{
    const int Hout = H + 8, Wout = W + 8;
    const int nT = Co / 16;
    int bi = blockIdx.x;
    const int y = bi % Hout; bi /= Hout;
    const int ot = bi % nT;  const int b = bi / nT;
    const int o0 = ot * 16;
    const int x = threadIdx.x;
    if (x >= Wout) return;
    float acc[16];
    #pragma unroll
    for (int k = 0; k < 16; ++k) acc[k] = 0.f;
    if (y >= 4 && y < H + 4 && x >= 4 && x < W + 4) {
        for (int c = 0; c < Co; ++c) {
            float v = img[(((size_t)b * Co + c) * H + (y - 4)) * W + (x - 4)];
            #pragma unroll
            for (int k = 0; k < 16; ++k) acc[k] = fmaf(fwT[c * Co + o0 + k], v, acc[k]);
        }
    }
    #pragma unroll
    for (int k = 0; k < 16; ++k)
        Xn[(((size_t)b * Co + o0 + k) * Hout + y) * Wout + x] = acc[k] + fb[o0 + k];
}

// ---------------- final linear: (16, 128*96*96) @ (10, feat)^T + b ----------------
__global__ __launch_bounds__(256) void linear_kernel(
    const float* __restrict__ Xf, const float* __restrict__ lw, const float* __restrict__ lb,
    float* __restrict__ out)
{
    const int b = blockIdx.x / 10, o = blockIdx.x % 10;
    const int feat = 128 * 96 * 96;
    const float4* xa = (const float4*)(Xf + (size_t)b * feat);
    const float4* wa = (const float4*)(lw + (size_t)o * feat);
    float acc = 0.f;
    for (int i = threadIdx.x; i < feat / 4; i += 256) {
        float4 xv = xa[i], wv = wa[i];
        acc += xv.x * wv.x + xv.y * wv.y + xv.z * wv.z + xv.w * wv.w;
    }
    for (int m = 32; m; m >>= 1) acc += __shfl_xor(acc, m);
    __shared__ float sm[4];
    if ((threadIdx.x & 63) == 0) sm[threadIdx.x >> 6] = acc;
    __syncthreads();
    if (threadIdx.x == 0) out[blockIdx.x] = sm[0] + sm[1] + sm[2] + sm[3] + lb[o];
}

// ---------------- host driver ----------------
template<int CIN, int C, int CO>
static void run_layer(const float* Xin, int H, int nP, const float* const* Lw,
                      const float* rw, const float* rb,
                      float* w3, float* fwT, float* scores, float* gate,
                      float* img, float* Xn, hipStream_t stream)
{
    const int W = H;
    const int P = nP * nP;
    const int BP = NB * P;
    const float* pw = Lw[0]; const float* pb = Lw[1];
    const float* ew = Lw[2]; const float* ebias = Lw[3];
    const float* fw = Lw[4]; const float* fb = Lw[5];

    repack_w_kernel<<<128, 256, 0, stream>>>(ew, w3, CO, C);
    repack_fin_kernel<<<(CO * CO + 255) / 256, 256, 0, stream>>>(fw, fwT, CO);
    router_kernel<CIN, C><<<BP / 4, 256, 0, stream>>>(Xin, pw, pb, rw, rb, scores, H, W, nP);
    gate_kernel<<<1, 256, 0, stream>>>(scores, BP, gate);
    expert_kernel<CIN, C, CO><<<BP, 256, 0, stream>>>(Xin, w3, ebias, scores, gate, img, H, W, nP);
    fin_kernel<<<NB * (CO / 16) * (H + 8), 128, 0, stream>>>(img, fwT, fb, Xn, CO, H, W);
}

extern "C" void kernel_launch(void* const* d_in, const int* in_sizes, int n_in,
                              void* d_out, int out_size, void* d_ws, size_t ws_size,
                              hipStream_t stream)
{
    const float* X0 = (const float*)d_in[0];
    const float* L[4][6];
    for (int l = 0; l < 4; ++l)
        for (int k = 0; k < 6; ++k) L[l][k] = (const float*)d_in[1 + l * 6 + k];
    const float* rw = (const float*)d_in[25];
    const float* rb = (const float*)d_in[26];
    const float* lw = (const float*)d_in[27];
    const float* lb = (const float*)d_in[28];

    // workspace layout (~141.5 MB total)
    char* ws = (char*)d_ws;
    const size_t IMG_B  = 63438848;   // 16*128*88*88*4  (max img)
    const size_t X_B    = 75497472;   // 16*128*96*96*4  (max X)
    const size_t W2_B   = 2433024;    // 512*132*9*4     (max repacked expert w)
    float* img    = (float*)(ws);
    float* bufX   = (float*)(ws + IMG_B);
    float* w3     = (float*)(ws + IMG_B + X_B);
    float* fwT    = (float*)(ws + IMG_B + X_B + W2_B);
    float* scores = fwT + 128 * 128;
    float* gate   = scores + 1936 * 4;

    // layer l: X (NB,CIN,H,H) -> img (NB,CO,H,H) -> X_next (NB,CO,H+8,H+8)
    run_layer<3,   7,   64>(X0,   64,  8, L[0], rw, rb, w3, fwT, scores, gate, img, bufX, stream);
    run_layer<64,  68,  64>(bufX, 72,  9, L[1], rw, rb, w3, fwT, scores, gate, img, bufX, stream);
    run_layer<64,  68, 128>(bufX, 80, 10, L[2], rw, rb, w3, fwT, scores, gate, img, bufX, stream);
    run_layer<128, 132, 128>(bufX, 88, 11, L[3], rw, rb, w3, fwT, scores, gate, img, bufX, stream);

    linear_kernel<<<160, 256, 0, stream>>>(bufX, lw, lb, (float*)d_out);
}

// Round 5
// 5841.529 us; speedup vs baseline: 1.6267x; 1.6267x over previous
//
#include <hip/hip_runtime.h>
#include <math.h>

#define NB 16
#define NE 4
#define THRESH 0.2f

// ---------------- repack kernels ----------------
// ew layout: ((e*CO + co)*C + c)*9 + ij  ->  w3: ((c*9 + ij)*CO + co)*NE + e
// so per (c,ij) a wave's 8-co x 4-e slice is 32 contiguous floats = 8 float4s,
// and each float4 holds the 4 experts' weights for one co.
__global__ void repack_w_kernel(const float* __restrict__ ew, float* __restrict__ w3,
                                int CO, int C) {
    int n = NE * CO * C * 9;
    for (int i = blockIdx.x * blockDim.x + threadIdx.x; i < n; i += gridDim.x * blockDim.x) {
        int ij = i % 9;
        int t = i / 9;
        int c = t % C; t /= C;
        int co = t % CO;
        int e = t / CO;
        w3[((size_t)(c * 9 + ij) * CO + co) * NE + e] = ew[i];
    }
}

// fwT[c*Co + o] = fw[o*Co + c]
__global__ void repack_fin_kernel(const float* __restrict__ fw, float* __restrict__ fwT, int Co) {
    int n = Co * Co;
    for (int i = blockIdx.x * blockDim.x + threadIdx.x; i < n; i += gridDim.x * blockDim.x) {
        int o = i / Co, c = i % Co;
        fwT[c * Co + o] = fw[i];
    }
}

// ---------------- router: pooled conv -> softmax scores ----------------
template<int CIN, int C>
__global__ __launch_bounds__(256) void router_kernel(
    const float* __restrict__ X, const float* __restrict__ pw, const float* __restrict__ pb,
    const float* __restrict__ rw, const float* __restrict__ rb,
    float* __restrict__ scores, int H, int W, int nP)
{
    __shared__ float S[4][C * 9 + 8];
    const int wv = threadIdx.x >> 6;
    const int lane = threadIdx.x & 63;
    const int bp = blockIdx.x * 4 + wv;
    const int P = nP * nP;
    const int b = bp / P, pi = bp % P;
    const int py = pi / nP, px = pi % nP;
    const int h = lane >> 3, w = lane & 7;
    const int gy = py * 8 + h, gx = px * 8 + w;
    float* Sw = S[wv];
    for (int c = 0; c < C; ++c) {
        float v;
        if (c < CIN) {
            v = X[(((size_t)b * CIN + c) * H + gy) * W + gx];
        } else {
            float t = (c == CIN || c == CIN + 2) ? gx * (1.f / (W - 1)) : gy * (1.f / (H - 1));
            v = (c >= CIN + 2) ? sinf(3.14159265358979323846f * t) : t;
        }
        float r = v;                       // row sums: lanes grouped by h (8 consecutive)
        r += __shfl_xor(r, 1); r += __shfl_xor(r, 2); r += __shfl_xor(r, 4);
        float cc = v;                      // col sums: lanes grouped by w
        cc += __shfl_xor(cc, 8); cc += __shfl_xor(cc, 16); cc += __shfl_xor(cc, 32);
        float T = r;
        T += __shfl_xor(T, 8); T += __shfl_xor(T, 16); T += __shfl_xor(T, 32);
        float R0 = __shfl(r, 0), R7 = __shfl(r, 56);
        float C0 = __shfl(cc, 0), C7 = __shfl(cc, 7);
        float x00 = __shfl(v, 0), x07 = __shfl(v, 7);
        float x70 = __shfl(v, 56), x77 = __shfl(v, 63);
        if (lane < 9) {
            int i = lane / 3, j = lane % 3;
            float s = T;
            if (i == 0) s -= R7; else if (i == 2) s -= R0;
            if (j == 0) s -= C7; else if (j == 2) s -= C0;
            if (i == 0 && j == 0) s += x77;
            else if (i == 0 && j == 2) s += x70;
            else if (i == 2 && j == 0) s += x07;
            else if (i == 2 && j == 2) s += x00;
            Sw[c * 9 + lane] = s;
        }
    }
    __syncthreads();
    if (lane < 8) {
        const int o = lane;
        float acc = 0.f;
        for (int c = 0; c < C; ++c) {
            #pragma unroll
            for (int ij = 0; ij < 9; ++ij)
                acc += pw[(o * C + c) * 9 + ij] * Sw[c * 9 + ij];
        }
        Sw[C * 9 + o] = acc * (1.f / 64.f) + pb[o];
    }
    __syncthreads();
    if (lane == 0) {
        float lg[NE];
        float m = -1e30f;
        #pragma unroll
        for (int e = 0; e < NE; ++e) {
            float a = rb[e];
            #pragma unroll
            for (int o = 0; o < 8; ++o) a += Sw[C * 9 + o] * rw[e * 8 + o];
            lg[e] = a;
            m = fmaxf(m, a);
        }
        float ssum = 0.f;
        #pragma unroll
        for (int e = 0; e < NE; ++e) { lg[e] = __expf(lg[e] - m); ssum += lg[e]; }
        float inv = 1.f / ssum;
        #pragma unroll
        for (int e = 0; e < NE; ++e) scores[bp * NE + e] = lg[e] * inv;
    }
}

// ---------------- gate: per-expert global max > THRESH ----------------
__global__ __launch_bounds__(256) void gate_kernel(const float* __restrict__ scores, int BP,
                                                   float* __restrict__ gate)
{
    __shared__ float sm[4][NE];
    float m[NE] = {-1e30f, -1e30f, -1e30f, -1e30f};
    for (int i = threadIdx.x; i < BP; i += 256) {
        #pragma unroll
        for (int e = 0; e < NE; ++e) m[e] = fmaxf(m[e], scores[i * NE + e]);
    }
    #pragma unroll
    for (int e = 0; e < NE; ++e) {
        float v = m[e];
        for (int o = 32; o; o >>= 1) v = fmaxf(v, __shfl_xor(v, o));
        m[e] = v;
    }
    int wv = threadIdx.x >> 6, lane = threadIdx.x & 63;
    if (lane == 0) {
        #pragma unroll
        for (int e = 0; e < NE; ++e) sm[wv][e] = m[e];
    }
    __syncthreads();
    if (threadIdx.x == 0) {
        #pragma unroll
        for (int e = 0; e < NE; ++e) {
            float mx = fmaxf(fmaxf(sm[0][e], sm[1][e]), fmaxf(sm[2][e], sm[3][e]));
            gate[e] = (mx > THRESH) ? 1.f : 0.f;
        }
    }
}

// ---------------- expert conv + relu + gated combine -> img ----------------
// one block per patch; padded patch in LDS; wave wv owns a CPW co-range, processed
// in tiles of 8 co x 4 experts (32 accumulators -- proven spill-free; 64 spilled
// in rounds 3/4). Per (c,ij) weights are read as 8 float4s (4x fewer load issues
// than round 1's 32 scalar loads); each float4 = 4 experts' weights for one co.
template<int CIN, int C, int CO>
__global__ __launch_bounds__(256, 2) void expert_kernel(
    const float* __restrict__ X, const float* __restrict__ w3, const float* __restrict__ eb,
    const float* __restrict__ scores, const float* __restrict__ gate,
    float* __restrict__ img, int H, int W, int nP)
{
    __shared__ float pat[C * 100];  // C x 10 x 10, zero border
    const int P = nP * nP;
    const int bp = blockIdx.x;
    const int b = bp / P, pi = bp % P;
    const int py = pi / nP, px = pi % nP;
    const int tid = threadIdx.x;

    for (int i = tid; i < C * 100; i += 256) pat[i] = 0.f;
    __syncthreads();
    for (int i = tid; i < C * 64; i += 256) {
        int c = i >> 6, p = i & 63, h = p >> 3, w = p & 7;
        int gy = py * 8 + h, gx = px * 8 + w;
        float v;
        if (c < CIN) {
            v = X[(((size_t)b * CIN + c) * H + gy) * W + gx];
        } else {
            float t = (c == CIN || c == CIN + 2) ? gx * (1.f / (W - 1)) : gy * (1.f / (H - 1));
            v = (c >= CIN + 2) ? sinf(3.14159265358979323846f * t) : t;
        }
        pat[c * 100 + (h + 1) * 10 + (w + 1)] = v;
    }
    __syncthreads();

    float sg[NE];
    #pragma unroll
    for (int e = 0; e < NE; ++e) sg[e] = scores[bp * NE + e] * gate[e];

    const int pix = tid & 63, h = pix >> 3, w = pix & 7, wv = tid >> 6;
    const int y = py * 8 + h, x = px * 8 + w;
    const int CPW = CO / 4;           // co per wave (16 or 32)
    const int base = h * 10 + w;      // tap (i,j) at base + i*10 + j in a 10x10 plane

    for (int co_t = 0; co_t < CPW; co_t += 8) {
        const int co0 = __builtin_amdgcn_readfirstlane(wv * CPW + co_t);
        float acc[NE][8];
        #pragma unroll
        for (int e = 0; e < NE; ++e)
            #pragma unroll
            for (int k = 0; k < 8; ++k) acc[e][k] = eb[e * CO + co0 + k];

        for (int c = 0; c < C; ++c) {
            float n[9];
            #pragma unroll
            for (int i = 0; i < 3; ++i)
                #pragma unroll
                for (int j = 0; j < 3; ++j) n[i * 3 + j] = pat[c * 100 + base + i * 10 + j];
            #pragma unroll
            for (int ij = 0; ij < 9; ++ij) {
                const float nv = n[ij];
                const float4* wq = (const float4*)(w3 + ((size_t)(c * 9 + ij) * CO + co0) * NE);
                #pragma unroll
                for (int k = 0; k < 8; ++k) {
                    float4 q = wq[k];               // 4 experts' weights for co0+k
                    acc[0][k] = fmaf(q.x, nv, acc[0][k]);
                    acc[1][k] = fmaf(q.y, nv, acc[1][k]);
                    acc[2][k] = fmaf(q.z, nv, acc[2][k]);
                    acc[3][k] = fmaf(q.w, nv, acc[3][k]);
                }
            }
        }
        #pragma unroll
        for (int k = 0; k < 8; ++k) {
            float cv = 0.f;
            #pragma unroll
            for (int e = 0; e < NE; ++e) cv += sg[e] * fmaxf(acc[e][k], 0.f);
            img[(((size_t)b * CO + co0 + k) * H + y) * W + x] = cv;
        }
    }
}

// ---------------- fin: 1x1 conv with pad 4 (border = bias) ----------------
__global__ __launch_bounds__(128) void fin_kernel(
    const float* __restrict__ img, const float* __restrict__ fwT, const float* __restrict__ fb,
    float* __restrict__ Xn, int Co, int H, int W)
{
    const int Hout = H + 8, Wout = W + 8;
    const int nT = Co / 16;
    int bi = blockIdx.x;
    const int y = bi % Hout; bi /= Hout;
    const int ot = bi % nT;  const int b = bi / nT;
    const int o0 = ot * 16;
    const int x = threadIdx.x;
    if (x >= Wout) return;
    float acc[16];
    #pragma unroll
    for (int k = 0; k < 16; ++k) acc[k] = 0.f;
    if (y >= 4 && y < H + 4 && x >= 4 && x < W + 4) {
        for (int c = 0; c < Co; ++c) {
            float v = img[(((size_t)b * Co + c) * H + (y - 4)) * W + (x - 4)];
            #pragma unroll
            for (int k = 0; k < 16; ++k) acc[k] = fmaf(fwT[c * Co + o0 + k], v, acc[k]);
        }
    }
    #pragma unroll
    for (int k = 0; k < 16; ++k)
        Xn[(((size_t)b * Co + o0 + k) * Hout + y) * Wout + x] = acc[k] + fb[o0 + k];
}

// ---------------- final linear: (16, 128*96*96) @ (10, feat)^T + b ----------------
__global__ __launch_bounds__(256) void linear_kernel(
    const float* __restrict__ Xf, const float* __restrict__ lw, const float* __restrict__ lb,
    float* __restrict__ out)
{
    const int b = blockIdx.x / 10, o = blockIdx.x % 10;
    const int feat = 128 * 96 * 96;
    const float4* xa = (const float4*)(Xf + (size_t)b * feat);
    const float4* wa = (const float4*)(lw + (size_t)o * feat);
    float acc = 0.f;
    for (int i = threadIdx.x; i < feat / 4; i += 256) {
        float4 xv = xa[i], wv = wa[i];
        acc += xv.x * wv.x + xv.y * wv.y + xv.z * wv.z + xv.w * wv.w;
    }
    for (int m = 32; m; m >>= 1) acc += __shfl_xor(acc, m);
    __shared__ float sm[4];
    if ((threadIdx.x & 63) == 0) sm[threadIdx.x >> 6] = acc;
    __syncthreads();
    if (threadIdx.x == 0) out[blockIdx.x] = sm[0] + sm[1] + sm[2] + sm[3] + lb[o];
}

// ---------------- host driver ----------------
template<int CIN, int C, int CO>
static void run_layer(const float* Xin, int H, int nP, const float* const* Lw,
                      const float* rw, const float* rb,
                      float* w3, float* fwT, float* scores, float* gate,
                      float* img, float* Xn, hipStream_t stream)
{
    const int W = H;
    const int P = nP * nP;
    const int BP = NB * P;
    const float* pw = Lw[0]; const float* pb = Lw[1];
    const float* ew = Lw[2]; const float* ebias = Lw[3];
    const float* fw = Lw[4]; const float* fb = Lw[5];

    repack_w_kernel<<<128, 256, 0, stream>>>(ew, w3, CO, C);
    repack_fin_kernel<<<(CO * CO + 255) / 256, 256, 0, stream>>>(fw, fwT, CO);
    router_kernel<CIN, C><<<BP / 4, 256, 0, stream>>>(Xin, pw, pb, rw, rb, scores, H, W, nP);
    gate_kernel<<<1, 256, 0, stream>>>(scores, BP, gate);
    expert_kernel<CIN, C, CO><<<BP, 256, 0, stream>>>(Xin, w3, ebias, scores, gate, img, H, W, nP);
    fin_kernel<<<NB * (CO / 16) * (H + 8), 128, 0, stream>>>(img, fwT, fb, Xn, CO, H, W);
}

extern "C" void kernel_launch(void* const* d_in, const int* in_sizes, int n_in,
                              void* d_out, int out_size, void* d_ws, size_t ws_size,
                              hipStream_t stream)
{
    const float* X0 = (const float*)d_in[0];
    const float* L[4][6];
    for (int l = 0; l < 4; ++l)
        for (int k = 0; k < 6; ++k) L[l][k] = (const float*)d_in[1 + l * 6 + k];
    const float* rw = (const float*)d_in[25];
    const float* rb = (const float*)d_in[26];
    const float* lw = (const float*)d_in[27];
    const float* lb = (const float*)d_in[28];

    // workspace layout (~141.5 MB total)
    char* ws = (char*)d_ws;
    const size_t IMG_B  = 63438848;   // 16*128*88*88*4  (max img)
    const size_t X_B    = 75497472;   // 16*128*96*96*4  (max X)
    const size_t W2_B   = 2433024;    // 512*132*9*4     (max repacked expert w)
    float* img    = (float*)(ws);
    float* bufX   = (float*)(ws + IMG_B);
    float* w3     = (float*)(ws + IMG_B + X_B);
    float* fwT    = (float*)(ws + IMG_B + X_B + W2_B);
    float* scores = fwT + 128 * 128;
    float* gate   = scores + 1936 * 4;

    // layer l: X (NB,CIN,H,H) -> img (NB,CO,H,H) -> X_next (NB,CO,H+8,H+8)
    run_layer<3,   7,   64>(X0,   64,  8, L[0], rw, rb, w3, fwT, scores, gate, img, bufX, stream);
    run_layer<64,  68,  64>(bufX, 72,  9, L[1], rw, rb, w3, fwT, scores, gate, img, bufX, stream);
    run_layer<64,  68, 128>(bufX, 80, 10, L[2], rw, rb, w3, fwT, scores, gate, img, bufX, stream);
    run_layer<128, 132, 128>(bufX, 88, 11, L[3], rw, rb, w3, fwT, scores, gate, img, bufX, stream);

    linear_kernel<<<160, 256, 0, stream>>>(bufX, lw, lb, (float*)d_out);
}

// Round 6
// 2265.282 us; speedup vs baseline: 4.1949x; 2.5787x over previous
//
#include <hip/hip_runtime.h>
#include <math.h>

#define NB 16
#define NE 4
#define THRESH 0.2f

typedef __attribute__((ext_vector_type(8))) __bf16 bf16x8;
typedef __attribute__((ext_vector_type(4))) float f32x4;
typedef unsigned short u16;
typedef unsigned int u32;

__device__ inline u16 bf16_rne(float v) {
    u32 u = __float_as_uint(v);
    u32 r = (u + 0x7fffu + ((u >> 16) & 1u)) >> 16;
    return (u16)r;
}
__device__ inline float bf16f(u16 h) { return __uint_as_float(((u32)h) << 16); }

// ---------------- weight repack: fp32 -> bf16 hi/lo, [ij][m=e*CO+co][Cpad] ----------------
// ew layout: ((e*CO+co)*C + c)*9 + ij = (m*C + c)*9 + ij
__global__ void repack_wexp_kernel(const float* __restrict__ ew, u16* __restrict__ WrHi,
                                   u16* __restrict__ WrLo, int CO, int C, int Cpad) {
    int n = 9 * NE * CO * Cpad;
    for (int i = blockIdx.x * blockDim.x + threadIdx.x; i < n; i += gridDim.x * blockDim.x) {
        int cp = i % Cpad;
        int t = i / Cpad;
        int m = t % (NE * CO);
        int ij = t / (NE * CO);
        float v = 0.f;
        if (cp < C) v = ew[(m * C + cp) * 9 + ij];
        u16 hb = bf16_rne(v);
        float lv = v - bf16f(hb);
        WrHi[i] = hb;
        WrLo[i] = bf16_rne(lv);
    }
}

// fwT[c*Co + o] = fw[o*Co + c]
__global__ void repack_fin_kernel(const float* __restrict__ fw, float* __restrict__ fwT, int Co) {
    int n = Co * Co;
    for (int i = blockIdx.x * blockDim.x + threadIdx.x; i < n; i += gridDim.x * blockDim.x) {
        int o = i / Co, c = i % Co;
        fwT[c * Co + o] = fw[i];
    }
}

// ---------------- router: pooled conv -> softmax scores ----------------
template<int CIN, int C>
__global__ __launch_bounds__(256) void router_kernel(
    const float* __restrict__ X, const float* __restrict__ pw, const float* __restrict__ pb,
    const float* __restrict__ rw, const float* __restrict__ rb,
    float* __restrict__ scores, int H, int W, int nP)
{
    __shared__ float S[4][C * 9 + 8];
    const int wv = threadIdx.x >> 6;
    const int lane = threadIdx.x & 63;
    const int bp = blockIdx.x * 4 + wv;
    const int P = nP * nP;
    const int b = bp / P, pi = bp % P;
    const int py = pi / nP, px = pi % nP;
    const int h = lane >> 3, w = lane & 7;
    const int gy = py * 8 + h, gx = px * 8 + w;
    float* Sw = S[wv];
    for (int c = 0; c < C; ++c) {
        float v;
        if (c < CIN) {
            v = X[(((size_t)b * CIN + c) * H + gy) * W + gx];
        } else {
            float t = (c == CIN || c == CIN + 2) ? gx * (1.f / (W - 1)) : gy * (1.f / (H - 1));
            v = (c >= CIN + 2) ? sinf(3.14159265358979323846f * t) : t;
        }
        float r = v;
        r += __shfl_xor(r, 1); r += __shfl_xor(r, 2); r += __shfl_xor(r, 4);
        float cc = v;
        cc += __shfl_xor(cc, 8); cc += __shfl_xor(cc, 16); cc += __shfl_xor(cc, 32);
        float T = r;
        T += __shfl_xor(T, 8); T += __shfl_xor(T, 16); T += __shfl_xor(T, 32);
        float R0 = __shfl(r, 0), R7 = __shfl(r, 56);
        float C0 = __shfl(cc, 0), C7 = __shfl(cc, 7);
        float x00 = __shfl(v, 0), x07 = __shfl(v, 7);
        float x70 = __shfl(v, 56), x77 = __shfl(v, 63);
        if (lane < 9) {
            int i = lane / 3, j = lane % 3;
            float s = T;
            if (i == 0) s -= R7; else if (i == 2) s -= R0;
            if (j == 0) s -= C7; else if (j == 2) s -= C0;
            if (i == 0 && j == 0) s += x77;
            else if (i == 0 && j == 2) s += x70;
            else if (i == 2 && j == 0) s += x07;
            else if (i == 2 && j == 2) s += x00;
            Sw[c * 9 + lane] = s;
        }
    }
    __syncthreads();
    if (lane < 8) {
        const int o = lane;
        float acc = 0.f;
        for (int c = 0; c < C; ++c) {
            #pragma unroll
            for (int ij = 0; ij < 9; ++ij)
                acc += pw[(o * C + c) * 9 + ij] * Sw[c * 9 + ij];
        }
        Sw[C * 9 + o] = acc * (1.f / 64.f) + pb[o];
    }
    __syncthreads();
    if (lane == 0) {
        float lg[NE];
        float m = -1e30f;
        #pragma unroll
        for (int e = 0; e < NE; ++e) {
            float a = rb[e];
            #pragma unroll
            for (int o = 0; o < 8; ++o) a += Sw[C * 9 + o] * rw[e * 8 + o];
            lg[e] = a;
            m = fmaxf(m, a);
        }
        float ssum = 0.f;
        #pragma unroll
        for (int e = 0; e < NE; ++e) { lg[e] = __expf(lg[e] - m); ssum += lg[e]; }
        float inv = 1.f / ssum;
        #pragma unroll
        for (int e = 0; e < NE; ++e) scores[bp * NE + e] = lg[e] * inv;
    }
}

// ---------------- gate: per-expert global max > THRESH ----------------
__global__ __launch_bounds__(256) void gate_kernel(const float* __restrict__ scores, int BP,
                                                   float* __restrict__ gate)
{
    __shared__ float sm[4][NE];
    float m[NE] = {-1e30f, -1e30f, -1e30f, -1e30f};
    for (int i = threadIdx.x; i < BP; i += 256) {
        #pragma unroll
        for (int e = 0; e < NE; ++e) m[e] = fmaxf(m[e], scores[i * NE + e]);
    }
    #pragma unroll
    for (int e = 0; e < NE; ++e) {
        float v = m[e];
        for (int o = 32; o; o >>= 1) v = fmaxf(v, __shfl_xor(v, o));
        m[e] = v;
    }
    int wv = threadIdx.x >> 6, lane = threadIdx.x & 63;
    if (lane == 0) {
        #pragma unroll
        for (int e = 0; e < NE; ++e) sm[wv][e] = m[e];
    }
    __syncthreads();
    if (threadIdx.x == 0) {
        #pragma unroll
        for (int e = 0; e < NE; ++e) {
            float mx = fmaxf(fmaxf(sm[0][e], sm[1][e]), fmaxf(sm[2][e], sm[3][e]));
            gate[e] = (mx > THRESH) ? 1.f : 0.f;
        }
    }
}

// ---------------- expert: MFMA bf16x3-split implicit GEMM ----------------
// Per block = one patch. GEMM: [M=NE*CO] x [K=Cpad*9] x [N=64 pixels].
// LDS: patT[2][pix10][Cpad(+8 pad)] bf16 (hi,lo). B-frag: ds_read_b128 of 8
// contiguous c at tap-shifted pixel. A (weights) pre-repacked [ij][m][Cpad]
// bf16 hi/lo -> 16B/lane global loads. Wave owns 32-co range for all 4 experts
// (combine over e register-local); 2 passes of 16-co keep acc at 64 VGPRs.
// fp32 = hi+lo split; products ah*bh + ah*bl + al*bh (error ~2^-18 rel).
template<int CIN, int C, int CO, int Cpad>
__global__ __launch_bounds__(256, 2) void expert_mfma_kernel(
    const float* __restrict__ X, const u16* __restrict__ WrHi, const u16* __restrict__ WrLo,
    const float* __restrict__ eb, const float* __restrict__ scores, const float* __restrict__ gate,
    float* __restrict__ img, int H, int W, int nP)
{
    constexpr int M = NE * CO;
    constexpr int KS = Cpad / 32;            // K-steps of 32 per tap
    constexpr int SPITCH = Cpad + 8;         // u16 pitch per pixel row (+16B bank pad)
    constexpr int NT = (CO == 128) ? 4 : 2;  // N-tiles per wave
    __shared__ __align__(16) u16 pat[2][100 * SPITCH];

    const int P = nP * nP;
    const int bp = blockIdx.x;
    const int b = bp / P, pi = bp % P;
    const int py = pi / nP, px = pi % nP;
    const int tid = threadIdx.x;

    // zero both LDS planes (2*100*SPITCH u16 == 100*SPITCH u32)
    u32* pz = (u32*)&pat[0][0];
    for (int i = tid; i < 100 * SPITCH; i += 256) pz[i] = 0;
    __syncthreads();
    // fill interior pixels, c < C (coalesced on gx)
    for (int i = tid; i < C * 64; i += 256) {
        int c = i >> 6, p = i & 63, h = p >> 3, w = p & 7;
        int gy = py * 8 + h, gx = px * 8 + w;
        float v;
        if (c < CIN) {
            v = X[(((size_t)b * CIN + c) * H + gy) * W + gx];
        } else {
            float t = (c == CIN || c == CIN + 2) ? gx * (1.f / (W - 1)) : gy * (1.f / (H - 1));
            v = (c >= CIN + 2) ? sinf(3.14159265358979323846f * t) : t;
        }
        u16 hb = bf16_rne(v);
        float lv = v - bf16f(hb);
        int a = ((h + 1) * 10 + (w + 1)) * SPITCH + c;
        pat[0][a] = hb;
        pat[1][a] = bf16_rne(lv);
    }
    __syncthreads();

    float sg[NE];
    #pragma unroll
    for (int e = 0; e < NE; ++e) sg[e] = scores[bp * NE + e] * gate[e];

    const int lane = tid & 63, wv = tid >> 6;
    const int colp = lane & 15;   // B col / D col = pixel-in-tile ; A row
    const int kg   = lane >> 4;   // k-group (8 contiguous k each); D row-group
    const int co0  = (CO == 128) ? wv * 32 : (wv >> 1) * 32;
    const int nt0  = (CO == 128) ? 0 : (wv & 1) * 2;

    // per-nt LDS base (output pixel position), tap/k added as offsets
    const u16* bbase[NT];
    #pragma unroll
    for (int nt = 0; nt < NT; ++nt) {
        int pix = (nt0 + nt) * 16 + colp;
        bbase[nt] = &pat[0][((pix >> 3) * 10 + (pix & 7)) * SPITCH + kg * 8];
    }
    const int aoff_lane = colp * Cpad + kg * 8;

    for (int pass = 0; pass < 2; ++pass) {
        f32x4 acc[NE][NT];
        #pragma unroll
        for (int e = 0; e < NE; ++e)
            #pragma unroll
            for (int nt = 0; nt < NT; ++nt) acc[e][nt] = (f32x4){0.f, 0.f, 0.f, 0.f};

        for (int ij = 0; ij < 9; ++ij) {
            const int tap = (ij / 3) * 11 + (ij % 3) - (ij / 3) * 1; // (i*10+j), see below
            const int tap10 = (ij / 3) * 10 + (ij % 3);
            (void)tap;
            const u16* WH = WrHi + (size_t)ij * M * Cpad + (co0 + pass * 16) * Cpad + aoff_lane;
            const u16* WL = WrLo + (size_t)ij * M * Cpad + (co0 + pass * 16) * Cpad + aoff_lane;
            #pragma unroll
            for (int ks = 0; ks < KS; ++ks) {
                bf16x8 bh[NT], bl[NT], ah[NE], al[NE];
                #pragma unroll
                for (int nt = 0; nt < NT; ++nt) {
                    const u16* pB = bbase[nt] + tap10 * SPITCH + ks * 32;
                    bh[nt] = *(const bf16x8*)(pB);
                    bl[nt] = *(const bf16x8*)(pB + 100 * SPITCH);
                }
                #pragma unroll
                for (int e = 0; e < NE; ++e) {
                    ah[e] = *(const bf16x8*)(WH + (size_t)e * CO * Cpad + ks * 32);
                    al[e] = *(const bf16x8*)(WL + (size_t)e * CO * Cpad + ks * 32);
                }
                #pragma unroll
                for (int e = 0; e < NE; ++e)
                    #pragma unroll
                    for (int nt = 0; nt < NT; ++nt) {
                        acc[e][nt] = __builtin_amdgcn_mfma_f32_16x16x32_bf16(ah[e], bh[nt], acc[e][nt], 0, 0, 0);
                        acc[e][nt] = __builtin_amdgcn_mfma_f32_16x16x32_bf16(ah[e], bl[nt], acc[e][nt], 0, 0, 0);
                        acc[e][nt] = __builtin_amdgcn_mfma_f32_16x16x32_bf16(al[e], bh[nt], acc[e][nt], 0, 0, 0);
                    }
            }
        }
        // epilogue: D col=lane&15 (pixel), row=(lane>>4)*4+r (co within 16-row tile)
        #pragma unroll
        for (int nt = 0; nt < NT; ++nt) {
            int pix = (nt0 + nt) * 16 + colp;
            int y = py * 8 + (pix >> 3), x = px * 8 + (pix & 7);
            #pragma unroll
            for (int r = 0; r < 4; ++r) {
                int co = co0 + pass * 16 + kg * 4 + r;
                float cv = 0.f;
                #pragma unroll
                for (int e = 0; e < NE; ++e)
                    cv += sg[e] * fmaxf(acc[e][nt][r] + eb[e * CO + co], 0.f);
                img[(((size_t)b * CO + co) * H + y) * W + x] = cv;
            }
        }
    }
}

// ---------------- fin: 1x1 conv with pad 4 (border = bias) ----------------
__global__ __launch_bounds__(128) void fin_kernel(
    const float* __restrict__ img, const float* __restrict__ fwT, const float* __restrict__ fb,
    float* __restrict__ Xn, int Co, int H, int W)
{
    const int Hout = H + 8, Wout = W + 8;
    const int nT = Co / 16;
    int bi = blockIdx.x;
    const int y = bi % Hout; bi /= Hout;
    const int ot = bi % nT;  const int b = bi / nT;
    const int o0 = ot * 16;
    const int x = threadIdx.x;
    if (x >= Wout) return;
    float acc[16];
    #pragma unroll
    for (int k = 0; k < 16; ++k) acc[k] = 0.f;
    if (y >= 4 && y < H + 4 && x >= 4 && x < W + 4) {
        for (int c = 0; c < Co; ++c) {
            float v = img[(((size_t)b * Co + c) * H + (y - 4)) * W + (x - 4)];
            #pragma unroll
            for (int k = 0; k < 16; ++k) acc[k] = fmaf(fwT[c * Co + o0 + k], v, acc[k]);
        }
    }
    #pragma unroll
    for (int k = 0; k < 16; ++k)
        Xn[(((size_t)b * Co + o0 + k) * Hout + y) * Wout + x] = acc[k] + fb[o0 + k];
}

// ---------------- final linear ----------------
__global__ __launch_bounds__(256) void linear_kernel(
    const float* __restrict__ Xf, const float* __restrict__ lw, const float* __restrict__ lb,
    float* __restrict__ out)
{
    const int b = blockIdx.x / 10, o = blockIdx.x % 10;
    const int feat = 128 * 96 * 96;
    const float4* xa = (const float4*)(Xf + (size_t)b * feat);
    const float4* wa = (const float4*)(lw + (size_t)o * feat);
    float acc = 0.f;
    for (int i = threadIdx.x; i < feat / 4; i += 256) {
        float4 xv = xa[i], wv = wa[i];
        acc += xv.x * wv.x + xv.y * wv.y + xv.z * wv.z + xv.w * wv.w;
    }
    for (int m = 32; m; m >>= 1) acc += __shfl_xor(acc, m);
    __shared__ float sm[4];
    if ((threadIdx.x & 63) == 0) sm[threadIdx.x >> 6] = acc;
    __syncthreads();
    if (threadIdx.x == 0) out[blockIdx.x] = sm[0] + sm[1] + sm[2] + sm[3] + lb[o];
}

// ---------------- host driver ----------------
template<int CIN, int C, int CO, int Cpad>
static void run_layer(const float* Xin, int H, int nP, const float* const* Lw,
                      const float* rw, const float* rb,
                      u16* WrHi, u16* WrLo, float* fwT, float* scores, float* gate,
                      float* img, float* Xn, hipStream_t stream)
{
    const int W = H;
    const int P = nP * nP;
    const int BP = NB * P;
    const float* pw = Lw[0]; const float* pb = Lw[1];
    const float* ew = Lw[2]; const float* ebias = Lw[3];
    const float* fw = Lw[4]; const float* fb = Lw[5];

    repack_wexp_kernel<<<576, 256, 0, stream>>>(ew, WrHi, WrLo, CO, C, Cpad);
    repack_fin_kernel<<<(CO * CO + 255) / 256, 256, 0, stream>>>(fw, fwT, CO);
    router_kernel<CIN, C><<<BP / 4, 256, 0, stream>>>(Xin, pw, pb, rw, rb, scores, H, W, nP);
    gate_kernel<<<1, 256, 0, stream>>>(scores, BP, gate);
    expert_mfma_kernel<CIN, C, CO, Cpad><<<BP, 256, 0, stream>>>(
        Xin, WrHi, WrLo, ebias, scores, gate, img, H, W, nP);
    fin_kernel<<<NB * (CO / 16) * (H + 8), 128, 0, stream>>>(img, fwT, fb, Xn, CO, H, W);
}

extern "C" void kernel_launch(void* const* d_in, const int* in_sizes, int n_in,
                              void* d_out, int out_size, void* d_ws, size_t ws_size,
                              hipStream_t stream)
{
    const float* X0 = (const float*)d_in[0];
    const float* L[4][6];
    for (int l = 0; l < 4; ++l)
        for (int k = 0; k < 6; ++k) L[l][k] = (const float*)d_in[1 + l * 6 + k];
    const float* rw = (const float*)d_in[25];
    const float* rb = (const float*)d_in[26];
    const float* lw = (const float*)d_in[27];
    const float* lb = (const float*)d_in[28];

    // workspace layout (~142 MB)
    char* ws = (char*)d_ws;
    const size_t IMG_B = 63438848;   // 16*128*88*88*4  (max img)
    const size_t X_B   = 75497472;   // 16*128*96*96*4  (max X)
    const size_t WR_B  = 1474560;    // 9*512*160*2     (max bf16 weight plane)
    float* img    = (float*)(ws);
    float* bufX   = (float*)(ws + IMG_B);
    u16*   WrHi   = (u16*)(ws + IMG_B + X_B);
    u16*   WrLo   = (u16*)(ws + IMG_B + X_B + WR_B);
    float* fwT    = (float*)(ws + IMG_B + X_B + 2 * WR_B);
    float* scores = fwT + 128 * 128;
    float* gate   = scores + 1936 * 4;

    // layer l: X (NB,CIN,H,H) -> img (NB,CO,H,H) -> X_next (NB,CO,H+8,H+8)
    run_layer<3,   7,   64,  32>(X0,   64,  8, L[0], rw, rb, WrHi, WrLo, fwT, scores, gate, img, bufX, stream);
    run_layer<64,  68,  64,  96>(bufX, 72,  9, L[1], rw, rb, WrHi, WrLo, fwT, scores, gate, img, bufX, stream);
    run_layer<64,  68, 128,  96>(bufX, 80, 10, L[2], rw, rb, WrHi, WrLo, fwT, scores, gate, img, bufX, stream);
    run_layer<128, 132, 128, 160>(bufX, 88, 11, L[3], rw, rb, WrHi, WrLo, fwT, scores, gate, img, bufX, stream);

    linear_kernel<<<160, 256, 0, stream>>>(bufX, lw, lb, (float*)d_out);
}

// Round 7
// 2169.311 us; speedup vs baseline: 4.3805x; 1.0442x over previous
//
#include <hip/hip_runtime.h>
#include <math.h>

#define NB 16
#define NE 4
#define THRESH 0.2f

typedef __attribute__((ext_vector_type(8))) _Float16 f16x8;
typedef __attribute__((ext_vector_type(4))) float f32x4;
typedef unsigned short u16;
typedef unsigned int u32;

__device__ inline u16 f16bits(float v) { _Float16 h = (_Float16)v; return __builtin_bit_cast(u16, h); }
__device__ inline float f16lo(float v) { _Float16 h = (_Float16)v; return v - (float)h; }

// ---------------- repack: expert weights (main+pos) and fin weights to fp16 hi/lo ----------------
// WmH/WmL: [ij][m=e*CO+co][CINp]   WpH/WpL: [m][64] (kp=pc*9+ij, <36 used)   fWH/fWL: [o][CO]
__global__ void repack_all_kernel(const float* __restrict__ ew, const float* __restrict__ fw,
    u16* __restrict__ WmH, u16* __restrict__ WmL, u16* __restrict__ WpH, u16* __restrict__ WpL,
    u16* __restrict__ fWH, u16* __restrict__ fWL, int CO, int CIN, int CINp, int C) {
    const int M = NE * CO;
    const int n1 = 9 * M * CINp, n2 = M * 64, n3 = CO * CO;
    const int n = n1 + n2 + n3;
    for (int i = blockIdx.x * blockDim.x + threadIdx.x; i < n; i += gridDim.x * blockDim.x) {
        if (i < n1) {
            int k = i % CINp; int t = i / CINp; int m = t % M; int ij = t / M;
            float v = (k < CIN) ? ew[(m * C + k) * 9 + ij] : 0.f;
            WmH[i] = f16bits(v); WmL[i] = f16bits(f16lo(v));
        } else if (i < n1 + n2) {
            int j = i - n1; int kp = j & 63; int m = j >> 6;
            float v = 0.f;
            if (kp < 36) { int pc = kp / 9, ij = kp % 9; v = ew[(m * C + CIN + pc) * 9 + ij]; }
            WpH[j] = f16bits(v); WpL[j] = f16bits(f16lo(v));
        } else {
            int j = i - n1 - n2;
            float v = fw[j];
            fWH[j] = f16bits(v); fWL[j] = f16bits(f16lo(v));
        }
    }
}

// ---------------- router: pooled conv -> softmax scores (unchanged, verified) ----------------
template<int CIN, int C>
__global__ __launch_bounds__(256) void router_kernel(
    const float* __restrict__ X, const float* __restrict__ pw, const float* __restrict__ pb,
    const float* __restrict__ rw, const float* __restrict__ rb,
    float* __restrict__ scores, int H, int W, int nP)
{
    __shared__ float S[4][C * 9 + 8];
    const int wv = threadIdx.x >> 6;
    const int lane = threadIdx.x & 63;
    const int bp = blockIdx.x * 4 + wv;
    const int P = nP * nP;
    const int b = bp / P, pi = bp % P;
    const int py = pi / nP, px = pi % nP;
    const int h = lane >> 3, w = lane & 7;
    const int gy = py * 8 + h, gx = px * 8 + w;
    float* Sw = S[wv];
    for (int c = 0; c < C; ++c) {
        float v;
        if (c < CIN) {
            v = X[(((size_t)b * CIN + c) * H + gy) * W + gx];
        } else {
            float t = (c == CIN || c == CIN + 2) ? gx * (1.f / (W - 1)) : gy * (1.f / (H - 1));
            v = (c >= CIN + 2) ? sinf(3.14159265358979323846f * t) : t;
        }
        float r = v;
        r += __shfl_xor(r, 1); r += __shfl_xor(r, 2); r += __shfl_xor(r, 4);
        float cc = v;
        cc += __shfl_xor(cc, 8); cc += __shfl_xor(cc, 16); cc += __shfl_xor(cc, 32);
        float T = r;
        T += __shfl_xor(T, 8); T += __shfl_xor(T, 16); T += __shfl_xor(T, 32);
        float R0 = __shfl(r, 0), R7 = __shfl(r, 56);
        float C0 = __shfl(cc, 0), C7 = __shfl(cc, 7);
        float x00 = __shfl(v, 0), x07 = __shfl(v, 7);
        float x70 = __shfl(v, 56), x77 = __shfl(v, 63);
        if (lane < 9) {
            int i = lane / 3, j = lane % 3;
            float s = T;
            if (i == 0) s -= R7; else if (i == 2) s -= R0;
            if (j == 0) s -= C7; else if (j == 2) s -= C0;
            if (i == 0 && j == 0) s += x77;
            else if (i == 0 && j == 2) s += x70;
            else if (i == 2 && j == 0) s += x07;
            else if (i == 2 && j == 2) s += x00;
            Sw[c * 9 + lane] = s;
        }
    }
    __syncthreads();
    if (lane < 8) {
        const int o = lane;
        float acc = 0.f;
        for (int c = 0; c < C; ++c) {
            #pragma unroll
            for (int ij = 0; ij < 9; ++ij)
                acc += pw[(o * C + c) * 9 + ij] * Sw[c * 9 + ij];
        }
        Sw[C * 9 + o] = acc * (1.f / 64.f) + pb[o];
    }
    __syncthreads();
    if (lane == 0) {
        float lg[NE];
        float m = -1e30f;
        #pragma unroll
        for (int e = 0; e < NE; ++e) {
            float a = rb[e];
            #pragma unroll
            for (int o = 0; o < 8; ++o) a += Sw[C * 9 + o] * rw[e * 8 + o];
            lg[e] = a;
            m = fmaxf(m, a);
        }
        float ssum = 0.f;
        #pragma unroll
        for (int e = 0; e < NE; ++e) { lg[e] = __expf(lg[e] - m); ssum += lg[e]; }
        float inv = 1.f / ssum;
        #pragma unroll
        for (int e = 0; e < NE; ++e) scores[bp * NE + e] = lg[e] * inv;
    }
}

// ---------------- gate ----------------
__global__ __launch_bounds__(256) void gate_kernel(const float* __restrict__ scores, int BP,
                                                   float* __restrict__ gate)
{
    __shared__ float sm[4][NE];
    float m[NE] = {-1e30f, -1e30f, -1e30f, -1e30f};
    for (int i = threadIdx.x; i < BP; i += 256) {
        #pragma unroll
        for (int e = 0; e < NE; ++e) m[e] = fmaxf(m[e], scores[i * NE + e]);
    }
    #pragma unroll
    for (int e = 0; e < NE; ++e) {
        float v = m[e];
        for (int o = 32; o; o >>= 1) v = fmaxf(v, __shfl_xor(v, o));
        m[e] = v;
    }
    int wv = threadIdx.x >> 6, lane = threadIdx.x & 63;
    if (lane == 0) {
        #pragma unroll
        for (int e = 0; e < NE; ++e) sm[wv][e] = m[e];
    }
    __syncthreads();
    if (threadIdx.x == 0) {
        #pragma unroll
        for (int e = 0; e < NE; ++e) {
            float mx = fmaxf(fmaxf(sm[0][e], sm[1][e]), fmaxf(sm[2][e], sm[3][e]));
            gate[e] = (mx > THRESH) ? 1.f : 0.f;
        }
    }
}

// ---------------- border: Xn border pixels = fin bias ----------------
__global__ __launch_bounds__(256) void border_kernel(float* __restrict__ Xn,
                                                     const float* __restrict__ fb,
                                                     int CO, int H, int W)
{
    const int Hout = H + 8, Wout = W + 8;
    const int nb = 16 * H + 64;  // Hout*Wout - H*W  (W==H)
    const long total = (long)NB * CO * nb;
    for (long i = (long)blockIdx.x * blockDim.x + threadIdx.x; i < total;
         i += (long)gridDim.x * blockDim.x) {
        int j = (int)(i % nb); long t = i / nb; int o = (int)(t % CO); int b = (int)(t / CO);
        int y, x;
        if (j < 4 * Wout)       { y = j / Wout;             x = j % Wout; }
        else if (j < 8 * Wout)  { int j2 = j - 4 * Wout; y = H + 4 + j2 / Wout; x = j2 % Wout; }
        else                    { int j3 = j - 8 * Wout; y = 4 + j3 / 8;
                                  int c8 = j3 % 8; x = (c8 < 4) ? c8 : W + 4 + (c8 - 4); }
        Xn[(((size_t)b * CO + o) * Hout + y) * Wout + x] = fb[o];
    }
}

// ---------------- fused expert conv + relu + combine + fin 1x1 conv ----------------
// One block = one patch. Main GEMM [M=NE*CO]x[K=9*CIN]x[N=64] + pos GEMM (K=64, 36 used),
// fp16 2-term (weights hi/lo, activations single). Combined output -> LDS fp16 ->
// fin GEMM [CO]x[CO]x[64] -> Xn interior (border handled by border_kernel).
// Verified MFMA lane mapping (round 6): A[row=lane&15][k=(lane>>4)*8+j],
// B[col=lane&15][k=...], D[col=lane&15][row=(lane>>4)*4+r].
template<int CIN, int CINp, int CO>
__global__ __launch_bounds__(256, 2) void expert_fused_kernel(
    const float* __restrict__ X,
    const u16* __restrict__ WmH, const u16* __restrict__ WmL,
    const u16* __restrict__ WpH, const u16* __restrict__ WpL,
    const u16* __restrict__ fWH, const u16* __restrict__ fWL,
    const float* __restrict__ eb, const float* __restrict__ fb,
    const float* __restrict__ scores, const float* __restrict__ gate,
    float* __restrict__ Xn, int H, int W, int nP)
{
    constexpr int M = NE * CO;
    constexpr int KSM = CINp / 32;      // main k-steps per tap
    constexpr int SP = CINp + 8;        // pat pitch (u16), 16B-aligned rows, bank stride ≡4
    constexpr int PIP = 72;             // posim pitch
    constexpr int CP = CO + 8;          // comb pitch
    constexpr int PASSES = CO / 64;     // 2 for CO=128, 1 for CO=64

    __shared__ __align__(16) u16 pat[100 * SP];
    __shared__ __align__(16) u16 posim[64 * PIP];
    __shared__ __align__(16) u16 comb[64 * CP];
    __shared__ float pospix[4][64];

    const int P = nP * nP;
    const int bp = blockIdx.x;
    const int b = bp / P, pi = bp % P;
    const int py = pi / nP, px = pi % nP;
    const int tid = threadIdx.x;
    const int Hout = H + 8, Wout = W + 8;

    // zero pat halo
    for (int i = tid; i < 100 * SP / 2; i += 256) ((u32*)pat)[i] = 0;
    // pos values at the 64 patch pixels (4 channels)
    {
        int pc = tid >> 6, p = tid & 63;
        int gy = py * 8 + (p >> 3), gx = px * 8 + (p & 7);
        float t = (pc == 0 || pc == 2) ? gx * (1.f / (W - 1)) : gy * (1.f / (H - 1));
        pospix[pc][p] = (pc >= 2) ? sinf(3.14159265358979323846f * t) : t;
    }
    __syncthreads();
    // stage X channels (c < CIN) as fp16
    for (int i = tid; i < CIN * 64; i += 256) {
        int c = i >> 6, p = i & 63, h = p >> 3, w = p & 7;
        int gy = py * 8 + h, gx = px * 8 + w;
        float v = __builtin_nontemporal_load(&X[(((size_t)b * CIN + c) * H + gy) * W + gx]);
        pat[((h + 1) * 10 + (w + 1)) * SP + c] = f16bits(v);
    }
    // pos im2col: posim[pix][kp=pc*9+ij], clipped at patch border
    for (int i = tid; i < 64 * 64; i += 256) {
        int pix = i >> 6, kp = i & 63;
        float v = 0.f;
        if (kp < 36) {
            int pc = kp / 9, ij = kp % 9;
            int hh = (pix >> 3) + ij / 3 - 1, ww = (pix & 7) + ij % 3 - 1;
            if (hh >= 0 && hh < 8 && ww >= 0 && ww < 8) v = pospix[pc][hh * 8 + ww];
        }
        posim[pix * PIP + kp] = f16bits(v);
    }
    __syncthreads();

    float sg[NE];
    #pragma unroll
    for (int e = 0; e < NE; ++e) sg[e] = scores[bp * NE + e] * gate[e];

    const int lane = tid & 63, wv = tid >> 6;
    const int colp = lane & 15;
    const int kg = lane >> 4;
    const int CPW = CO / 4;

    int prow[4];
    #pragma unroll
    for (int nt = 0; nt < 4; ++nt) {
        int pix = nt * 16 + colp;
        prow[nt] = ((pix >> 3) * 10 + (pix & 7)) * SP;
    }

    for (int pass = 0; pass < PASSES; ++pass) {
        const int co0 = wv * CPW + pass * 16;
        f32x4 acc[NE][4];
        #pragma unroll
        for (int e = 0; e < NE; ++e)
            #pragma unroll
            for (int nt = 0; nt < 4; ++nt) acc[e][nt] = (f32x4){0.f, 0.f, 0.f, 0.f};

        // main taps: K = CIN per tap, exact
        for (int ij = 0; ij < 9; ++ij) {
            const int tap = (ij / 3) * 10 + (ij % 3);
            const u16* WHB = WmH + ((size_t)ij * M + co0 + colp) * CINp + kg * 8;
            const u16* WLB = WmL + ((size_t)ij * M + co0 + colp) * CINp + kg * 8;
            #pragma unroll
            for (int ks = 0; ks < KSM; ++ks) {
                f16x8 bv[4];
                #pragma unroll
                for (int nt = 0; nt < 4; ++nt)
                    bv[nt] = *(const f16x8*)&pat[prow[nt] + tap * SP + ks * 32 + kg * 8];
                #pragma unroll
                for (int e = 0; e < NE; ++e) {
                    f16x8 ah = *(const f16x8*)(WHB + (size_t)e * CO * CINp + ks * 32);
                    f16x8 al = *(const f16x8*)(WLB + (size_t)e * CO * CINp + ks * 32);
                    #pragma unroll
                    for (int nt = 0; nt < 4; ++nt) {
                        acc[e][nt] = __builtin_amdgcn_mfma_f32_16x16x32_f16(ah, bv[nt], acc[e][nt], 0, 0, 0);
                        acc[e][nt] = __builtin_amdgcn_mfma_f32_16x16x32_f16(al, bv[nt], acc[e][nt], 0, 0, 0);
                    }
                }
            }
        }
        // positional channels: K=64 (36 used)
        #pragma unroll
        for (int ks = 0; ks < 2; ++ks) {
            f16x8 bv[4];
            #pragma unroll
            for (int nt = 0; nt < 4; ++nt)
                bv[nt] = *(const f16x8*)&posim[(nt * 16 + colp) * PIP + ks * 32 + kg * 8];
            #pragma unroll
            for (int e = 0; e < NE; ++e) {
                const size_t ao = ((size_t)(e * CO + co0 + colp)) * 64 + ks * 32 + kg * 8;
                f16x8 ah = *(const f16x8*)(WpH + ao);
                f16x8 al = *(const f16x8*)(WpL + ao);
                #pragma unroll
                for (int nt = 0; nt < 4; ++nt) {
                    acc[e][nt] = __builtin_amdgcn_mfma_f32_16x16x32_f16(ah, bv[nt], acc[e][nt], 0, 0, 0);
                    acc[e][nt] = __builtin_amdgcn_mfma_f32_16x16x32_f16(al, bv[nt], acc[e][nt], 0, 0, 0);
                }
            }
        }
        // bias + relu + gated combine -> comb LDS (fp16)
        float ebv[NE][4];
        #pragma unroll
        for (int e = 0; e < NE; ++e)
            #pragma unroll
            for (int r = 0; r < 4; ++r) ebv[e][r] = eb[e * CO + co0 + kg * 4 + r];
        #pragma unroll
        for (int nt = 0; nt < 4; ++nt) {
            int pix = nt * 16 + colp;
            u16 hv[4];
            #pragma unroll
            for (int r = 0; r < 4; ++r) {
                float cv = 0.f;
                #pragma unroll
                for (int e = 0; e < NE; ++e)
                    cv += sg[e] * fmaxf(acc[e][nt][r] + ebv[e][r], 0.f);
                hv[r] = f16bits(cv);
            }
            uint2 q;
            q.x = (u32)hv[0] | ((u32)hv[1] << 16);
            q.y = (u32)hv[2] | ((u32)hv[3] << 16);
            *(uint2*)&comb[pix * CP + co0 + kg * 4] = q;
        }
    }
    __syncthreads();

    // fin GEMM: out[o][pix] = sum_c fw[o][c]*comb[pix][c]
    const int OPW = CO / 4;
    const int o0 = wv * OPW;
    for (int mt = 0; mt < OPW / 16; ++mt) {
        f32x4 accF[4];
        #pragma unroll
        for (int nt = 0; nt < 4; ++nt) accF[nt] = (f32x4){0.f, 0.f, 0.f, 0.f};
        #pragma unroll
        for (int ks = 0; ks < CO / 32; ++ks) {
            const size_t ao = (size_t)(o0 + mt * 16 + colp) * CO + ks * 32 + kg * 8;
            f16x8 ah = *(const f16x8*)(fWH + ao);
            f16x8 al = *(const f16x8*)(fWL + ao);
            #pragma unroll
            for (int nt = 0; nt < 4; ++nt) {
                f16x8 bv = *(const f16x8*)&comb[(nt * 16 + colp) * CP + ks * 32 + kg * 8];
                accF[nt] = __builtin_amdgcn_mfma_f32_16x16x32_f16(ah, bv, accF[nt], 0, 0, 0);
                accF[nt] = __builtin_amdgcn_mfma_f32_16x16x32_f16(al, bv, accF[nt], 0, 0, 0);
            }
        }
        #pragma unroll
        for (int nt = 0; nt < 4; ++nt) {
            int pix = nt * 16 + colp;
            int gy = py * 8 + (pix >> 3) + 4, gx = px * 8 + (pix & 7) + 4;
            #pragma unroll
            for (int r = 0; r < 4; ++r) {
                int o = o0 + mt * 16 + kg * 4 + r;
                __builtin_nontemporal_store(accF[nt][r] + fb[o],
                    &Xn[(((size_t)b * CO + o) * Hout + gy) * Wout + gx]);
            }
        }
    }
}

// ---------------- final linear ----------------
__global__ __launch_bounds__(256) void linear_kernel(
    const float* __restrict__ Xf, const float* __restrict__ lw, const float* __restrict__ lb,
    float* __restrict__ out)
{
    const int b = blockIdx.x / 10, o = blockIdx.x % 10;
    const int feat = 128 * 96 * 96;
    const float4* xa = (const float4*)(Xf + (size_t)b * feat);
    const float4* wa = (const float4*)(lw + (size_t)o * feat);
    float acc = 0.f;
    for (int i = threadIdx.x; i < feat / 4; i += 256) {
        float4 xv = xa[i], wv = wa[i];
        acc += xv.x * wv.x + xv.y * wv.y + xv.z * wv.z + xv.w * wv.w;
    }
    for (int m = 32; m; m >>= 1) acc += __shfl_xor(acc, m);
    __shared__ float sm[4];
    if ((threadIdx.x & 63) == 0) sm[threadIdx.x >> 6] = acc;
    __syncthreads();
    if (threadIdx.x == 0) out[blockIdx.x] = sm[0] + sm[1] + sm[2] + sm[3] + lb[o];
}

// ---------------- host driver ----------------
template<int CIN, int CINp, int CO>
static void run_layer(const float* Xin, int H, int nP, const float* const* Lw,
                      const float* rw, const float* rb,
                      u16* WmH, u16* WmL, u16* WpH, u16* WpL, u16* fWH, u16* fWL,
                      float* scores, float* gate, float* Xn, hipStream_t stream)
{
    const int W = H;
    const int BP = NB * nP * nP;
    const float* pw = Lw[0]; const float* pb = Lw[1];
    const float* ew = Lw[2]; const float* ebias = Lw[3];
    const float* fw = Lw[4]; const float* fb = Lw[5];

    repack_all_kernel<<<1024, 256, 0, stream>>>(ew, fw, WmH, WmL, WpH, WpL, fWH, fWL,
                                                CO, CIN, CINp, CIN + 4);
    router_kernel<CIN, CIN + 4><<<BP / 4, 256, 0, stream>>>(Xin, pw, pb, rw, rb, scores, H, W, nP);
    gate_kernel<<<1, 256, 0, stream>>>(scores, BP, gate);
    border_kernel<<<2048, 256, 0, stream>>>(Xn, fb, CO, H, W);
    expert_fused_kernel<CIN, CINp, CO><<<BP, 256, 0, stream>>>(
        Xin, WmH, WmL, WpH, WpL, fWH, fWL, ebias, fb, scores, gate, Xn, H, W, nP);
}

extern "C" void kernel_launch(void* const* d_in, const int* in_sizes, int n_in,
                              void* d_out, int out_size, void* d_ws, size_t ws_size,
                              hipStream_t stream)
{
    const float* X0 = (const float*)d_in[0];
    const float* L[4][6];
    for (int l = 0; l < 4; ++l)
        for (int k = 0; k < 6; ++k) L[l][k] = (const float*)d_in[1 + l * 6 + k];
    const float* rw = (const float*)d_in[25];
    const float* rb = (const float*)d_in[26];
    const float* lw = (const float*)d_in[27];
    const float* lb = (const float*)d_in[28];

    // workspace (~141.5 MB): ping-pong X buffers + fp16 weight planes
    char* ws = (char*)d_ws;
    const size_t XA_B = 63438848;    // 16*128*88*88*4 (L3 out, max for A)
    const size_t XB_B = 75497472;    // 16*128*96*96*4 (L4 out, max for B)
    const size_t WM_B = 1179648;     // 9*512*128*2
    const size_t WP_B = 65536;       // 512*64*2
    const size_t FW_B = 32768;       // 128*128*2
    float* XA = (float*)(ws);
    float* XB = (float*)(ws + XA_B);
    u16* WmH = (u16*)(ws + XA_B + XB_B);
    u16* WmL = (u16*)(ws + XA_B + XB_B + WM_B);
    u16* WpH = (u16*)(ws + XA_B + XB_B + 2 * WM_B);
    u16* WpL = (u16*)(ws + XA_B + XB_B + 2 * WM_B + WP_B);
    u16* fWH = (u16*)(ws + XA_B + XB_B + 2 * WM_B + 2 * WP_B);
    u16* fWL = (u16*)(ws + XA_B + XB_B + 2 * WM_B + 2 * WP_B + FW_B);
    float* scores = (float*)(ws + XA_B + XB_B + 2 * WM_B + 2 * WP_B + 2 * FW_B);
    float* gate = scores + 1936 * 4;

    // layer l: X (NB,CIN,H,H) -> Xn (NB,CO,H+8,H+8), ping-pong A/B
    run_layer<3,   32,  64>(X0, 64,  8, L[0], rw, rb, WmH, WmL, WpH, WpL, fWH, fWL, scores, gate, XA, stream);
    run_layer<64,  64,  64>(XA, 72,  9, L[1], rw, rb, WmH, WmL, WpH, WpL, fWH, fWL, scores, gate, XB, stream);
    run_layer<64,  64, 128>(XB, 80, 10, L[2], rw, rb, WmH, WmL, WpH, WpL, fWH, fWL, scores, gate, XA, stream);
    run_layer<128, 128, 128>(XA, 88, 11, L[3], rw, rb, WmH, WmL, WpH, WpL, fWH, fWL, scores, gate, XB, stream);

    linear_kernel<<<160, 256, 0, stream>>>(XB, lw, lb, (float*)d_out);
}

// Round 8
// 1345.002 us; speedup vs baseline: 7.0652x; 1.6129x over previous
//
#include <hip/hip_runtime.h>
#include <math.h>

#define NB 16
#define NE 4
#define THRESH 0.2f

typedef __attribute__((ext_vector_type(8))) _Float16 f16x8;
typedef __attribute__((ext_vector_type(4))) float f32x4;
typedef unsigned short u16;
typedef unsigned int u32;

__device__ inline u16 f16bits(float v) { _Float16 h = (_Float16)v; return __builtin_bit_cast(u16, h); }
__device__ inline float f16lo(float v) { _Float16 h = (_Float16)v; return v - (float)h; }

// ---------------- repack: expert weights (main+pos) and fin weights to fp16 hi/lo ----------------
// WmH/WmL: [ij][m=e*CO+co][CINp]   WpH/WpL: [m][64] (kp=pc*9+ij, <36 used)   fWH/fWL: [o][CO]
__global__ void repack_all_kernel(const float* __restrict__ ew, const float* __restrict__ fw,
    u16* __restrict__ WmH, u16* __restrict__ WmL, u16* __restrict__ WpH, u16* __restrict__ WpL,
    u16* __restrict__ fWH, u16* __restrict__ fWL, int CO, int CIN, int CINp, int C) {
    const int M = NE * CO;
    const int n1 = 9 * M * CINp, n2 = M * 64, n3 = CO * CO;
    const int n = n1 + n2 + n3;
    for (int i = blockIdx.x * blockDim.x + threadIdx.x; i < n; i += gridDim.x * blockDim.x) {
        if (i < n1) {
            int k = i % CINp; int t = i / CINp; int m = t % M; int ij = t / M;
            float v = (k < CIN) ? ew[(m * C + k) * 9 + ij] : 0.f;
            WmH[i] = f16bits(v); WmL[i] = f16bits(f16lo(v));
        } else if (i < n1 + n2) {
            int j = i - n1; int kp = j & 63; int m = j >> 6;
            float v = 0.f;
            if (kp < 36) { int pc = kp / 9, ij = kp % 9; v = ew[(m * C + CIN + pc) * 9 + ij]; }
            WpH[j] = f16bits(v); WpL[j] = f16bits(f16lo(v));
        } else {
            int j = i - n1 - n2;
            float v = fw[j];
            fWH[j] = f16bits(v); fWL[j] = f16bits(f16lo(v));
        }
    }
}

// ---------------- router: pooled conv -> softmax scores (verified) ----------------
template<int CIN, int C>
__global__ __launch_bounds__(256) void router_kernel(
    const float* __restrict__ X, const float* __restrict__ pw, const float* __restrict__ pb,
    const float* __restrict__ rw, const float* __restrict__ rb,
    float* __restrict__ scores, int H, int W, int nP)
{
    __shared__ float S[4][C * 9 + 8];
    const int wv = threadIdx.x >> 6;
    const int lane = threadIdx.x & 63;
    const int bp = blockIdx.x * 4 + wv;
    const int P = nP * nP;
    const int b = bp / P, pi = bp % P;
    const int py = pi / nP, px = pi % nP;
    const int h = lane >> 3, w = lane & 7;
    const int gy = py * 8 + h, gx = px * 8 + w;
    float* Sw = S[wv];
    for (int c = 0; c < C; ++c) {
        float v;
        if (c < CIN) {
            v = X[(((size_t)b * CIN + c) * H + gy) * W + gx];
        } else {
            float t = (c == CIN || c == CIN + 2) ? gx * (1.f / (W - 1)) : gy * (1.f / (H - 1));
            v = (c >= CIN + 2) ? sinf(3.14159265358979323846f * t) : t;
        }
        float r = v;
        r += __shfl_xor(r, 1); r += __shfl_xor(r, 2); r += __shfl_xor(r, 4);
        float cc = v;
        cc += __shfl_xor(cc, 8); cc += __shfl_xor(cc, 16); cc += __shfl_xor(cc, 32);
        float T = r;
        T += __shfl_xor(T, 8); T += __shfl_xor(T, 16); T += __shfl_xor(T, 32);
        float R0 = __shfl(r, 0), R7 = __shfl(r, 56);
        float C0 = __shfl(cc, 0), C7 = __shfl(cc, 7);
        float x00 = __shfl(v, 0), x07 = __shfl(v, 7);
        float x70 = __shfl(v, 56), x77 = __shfl(v, 63);
        if (lane < 9) {
            int i = lane / 3, j = lane % 3;
            float s = T;
            if (i == 0) s -= R7; else if (i == 2) s -= R0;
            if (j == 0) s -= C7; else if (j == 2) s -= C0;
            if (i == 0 && j == 0) s += x77;
            else if (i == 0 && j == 2) s += x70;
            else if (i == 2 && j == 0) s += x07;
            else if (i == 2 && j == 2) s += x00;
            Sw[c * 9 + lane] = s;
        }
    }
    __syncthreads();
    if (lane < 8) {
        const int o = lane;
        float acc = 0.f;
        for (int c = 0; c < C; ++c) {
            #pragma unroll
            for (int ij = 0; ij < 9; ++ij)
                acc += pw[(o * C + c) * 9 + ij] * Sw[c * 9 + ij];
        }
        Sw[C * 9 + o] = acc * (1.f / 64.f) + pb[o];
    }
    __syncthreads();
    if (lane == 0) {
        float lg[NE];
        float m = -1e30f;
        #pragma unroll
        for (int e = 0; e < NE; ++e) {
            float a = rb[e];
            #pragma unroll
            for (int o = 0; o < 8; ++o) a += Sw[C * 9 + o] * rw[e * 8 + o];
            lg[e] = a;
            m = fmaxf(m, a);
        }
        float ssum = 0.f;
        #pragma unroll
        for (int e = 0; e < NE; ++e) { lg[e] = __expf(lg[e] - m); ssum += lg[e]; }
        float inv = 1.f / ssum;
        #pragma unroll
        for (int e = 0; e < NE; ++e) scores[bp * NE + e] = lg[e] * inv;
    }
}

// ---------------- gate ----------------
__global__ __launch_bounds__(256) void gate_kernel(const float* __restrict__ scores, int BP,
                                                   float* __restrict__ gate)
{
    __shared__ float sm[4][NE];
    float m[NE] = {-1e30f, -1e30f, -1e30f, -1e30f};
    for (int i = threadIdx.x; i < BP; i += 256) {
        #pragma unroll
        for (int e = 0; e < NE; ++e) m[e] = fmaxf(m[e], scores[i * NE + e]);
    }
    #pragma unroll
    for (int e = 0; e < NE; ++e) {
        float v = m[e];
        for (int o = 32; o; o >>= 1) v = fmaxf(v, __shfl_xor(v, o));
        m[e] = v;
    }
    int wv = threadIdx.x >> 6, lane = threadIdx.x & 63;
    if (lane == 0) {
        #pragma unroll
        for (int e = 0; e < NE; ++e) sm[wv][e] = m[e];
    }
    __syncthreads();
    if (threadIdx.x == 0) {
        #pragma unroll
        for (int e = 0; e < NE; ++e) {
            float mx = fmaxf(fmaxf(sm[0][e], sm[1][e]), fmaxf(sm[2][e], sm[3][e]));
            gate[e] = (mx > THRESH) ? 1.f : 0.f;
        }
    }
}

// ---------------- border: Xn border pixels = fin bias ----------------
__global__ __launch_bounds__(256) void border_kernel(float* __restrict__ Xn,
                                                     const float* __restrict__ fb,
                                                     int CO, int H, int W)
{
    const int Hout = H + 8, Wout = W + 8;
    const int nb = 16 * H + 64;
    const long total = (long)NB * CO * nb;
    for (long i = (long)blockIdx.x * blockDim.x + threadIdx.x; i < total;
         i += (long)gridDim.x * blockDim.x) {
        int j = (int)(i % nb); long t = i / nb; int o = (int)(t % CO); int b = (int)(t / CO);
        int y, x;
        if (j < 4 * Wout)       { y = j / Wout;             x = j % Wout; }
        else if (j < 8 * Wout)  { int j2 = j - 4 * Wout; y = H + 4 + j2 / Wout; x = j2 % Wout; }
        else                    { int j3 = j - 8 * Wout; y = 4 + j3 / 8;
                                  int c8 = j3 % 8; x = (c8 < 4) ? c8 : W + 4 + (c8 - 4); }
        Xn[(((size_t)b * CO + o) * Hout + y) * Wout + x] = fb[o];
    }
}

// ---------------- fused expert + fin, 2 PATCHES PER BLOCK (512 threads, 8 waves) ----------------
// Weight traffic amortized over N=128: for CO=128, each wave owns one 16-co M-tile for
// all 4 experts across BOTH patches (8 N-tiles) -> block streams the hi/lo weight array
// ONCE per 2 patches (R7: once per patch per 4-wave block => 4.6 GB L2 traffic at L4).
// CO=64: waves split by patch (wv>>2); twin waves' duplicate A-loads hit L1.
template<int CIN, int CINp, int CO>
__global__ __launch_bounds__(512, 2) void expert_fused_kernel(
    const float* __restrict__ X,
    const u16* __restrict__ WmH, const u16* __restrict__ WmL,
    const u16* __restrict__ WpH, const u16* __restrict__ WpL,
    const u16* __restrict__ fWH, const u16* __restrict__ fWL,
    const float* __restrict__ eb, const float* __restrict__ fb,
    const float* __restrict__ scores, const float* __restrict__ gate,
    float* __restrict__ Xn, int H, int W, int nP)
{
    constexpr int M = NE * CO;
    constexpr int KSM = CINp / 32;
    constexpr int SP = CINp + 8;
    constexpr int PIP = 72;
    constexpr int CP = CO + 8;
    constexpr bool FAT = (CO == 128);
    constexpr int NT = FAT ? 8 : 4;

    __shared__ __align__(16) u16 pat[2 * 100 * SP];     // 2 patches, single fp16 plane
    __shared__ __align__(16) u16 posim[2 * 64 * PIP];
    __shared__ __align__(16) u16 comb[2 * 64 * CP];
    __shared__ float pospix[2][4][64];

    const int P = nP * nP;
    const int bp0 = blockIdx.x * 2, bp1 = bp0 + 1;
    const int b0 = bp0 / P, pi0 = bp0 % P, py0 = pi0 / nP, px0 = pi0 % nP;
    const int b1 = bp1 / P, pi1 = bp1 % P, py1 = pi1 / nP, px1 = pi1 % nP;
    const int tid = threadIdx.x;
    const int Hout = H + 8, Wout = W + 8;

    for (int i = tid; i < 100 * SP; i += 512) ((u32*)pat)[i] = 0;
    {
        int g = tid >> 8, r = tid & 255, pc = r >> 6, p = r & 63;
        int gy = (g ? py1 : py0) * 8 + (p >> 3), gx = (g ? px1 : px0) * 8 + (p & 7);
        float t = (pc == 0 || pc == 2) ? gx * (1.f / (W - 1)) : gy * (1.f / (H - 1));
        pospix[g][pc][p] = (pc >= 2) ? sinf(3.14159265358979323846f * t) : t;
    }
    __syncthreads();
    // stage X as fp16 (float4-vectorized reads)
    for (int i = tid; i < 2 * CIN * 16; i += 512) {
        int g = i / (CIN * 16), j = i % (CIN * 16);
        int c = j >> 4, q = j & 15, h = q >> 1, w4 = (q & 1) * 4;
        int bb = g ? b1 : b0, py = g ? py1 : py0, px = g ? px1 : px0;
        const float4 v = *(const float4*)&X[(((size_t)bb * CIN + c) * H + py * 8 + h) * W + px * 8 + w4];
        int base = g * 100 * SP + c;
        pat[base + ((h + 1) * 10 + (w4 + 1)) * SP] = f16bits(v.x);
        pat[base + ((h + 1) * 10 + (w4 + 2)) * SP] = f16bits(v.y);
        pat[base + ((h + 1) * 10 + (w4 + 3)) * SP] = f16bits(v.z);
        pat[base + ((h + 1) * 10 + (w4 + 4)) * SP] = f16bits(v.w);
    }
    // pos im2col (zero-halo at patch border, same as X channels)
    for (int i = tid; i < 2 * 64 * 64; i += 512) {
        int g = i >> 12, r = i & 4095, pix = r >> 6, kp = r & 63;
        float v = 0.f;
        if (kp < 36) {
            int pc = kp / 9, ij = kp % 9;
            int hh = (pix >> 3) + ij / 3 - 1, ww = (pix & 7) + ij % 3 - 1;
            if (hh >= 0 && hh < 8 && ww >= 0 && ww < 8) v = pospix[g][pc][hh * 8 + ww];
        }
        posim[g * 64 * PIP + pix * PIP + kp] = f16bits(v);
    }
    __syncthreads();

    const int lane = tid & 63, wv = tid >> 6;
    const int colp = lane & 15, kg = lane >> 4;
    const int cot = FAT ? wv : (wv & 3);
    const int gO = FAT ? 0 : (wv >> 2);
    const int co0 = cot * 16;

    int prow[NT];
    #pragma unroll
    for (int nt = 0; nt < NT; ++nt) {
        int g = FAT ? (nt >> 2) : gO;
        int pix = (nt & 3) * 16 + colp;
        prow[nt] = g * 100 * SP + ((pix >> 3) * 10 + (pix & 7)) * SP;
    }
    int aoff[NE];
    #pragma unroll
    for (int e = 0; e < NE; ++e)
        aoff[e] = (e * CO + co0 + colp) * CINp + kg * 8;

    f32x4 acc[NE][NT];
    #pragma unroll
    for (int e = 0; e < NE; ++e)
        #pragma unroll
        for (int nt = 0; nt < NT; ++nt) acc[e][nt] = (f32x4){0.f, 0.f, 0.f, 0.f};

    // main GEMM over 9 taps, K=CINp per tap
    for (int ij = 0; ij < 9; ++ij) {
        const int tap = (ij / 3) * 10 + (ij % 3);
        const int wb = ij * M * CINp;
        #pragma unroll
        for (int ks = 0; ks < KSM; ++ks) {
            f16x8 Bv[NT];
            #pragma unroll
            for (int nt = 0; nt < NT; ++nt)
                Bv[nt] = *(const f16x8*)&pat[prow[nt] + tap * SP + ks * 32 + kg * 8];
            #pragma unroll
            for (int e = 0; e < NE; ++e) {
                f16x8 Ah = *(const f16x8*)(WmH + wb + aoff[e] + ks * 32);
                f16x8 Al = *(const f16x8*)(WmL + wb + aoff[e] + ks * 32);
                __builtin_amdgcn_s_setprio(1);
                #pragma unroll
                for (int nt = 0; nt < NT; ++nt) {
                    acc[e][nt] = __builtin_amdgcn_mfma_f32_16x16x32_f16(Ah, Bv[nt], acc[e][nt], 0, 0, 0);
                    acc[e][nt] = __builtin_amdgcn_mfma_f32_16x16x32_f16(Al, Bv[nt], acc[e][nt], 0, 0, 0);
                }
                __builtin_amdgcn_s_setprio(0);
            }
        }
    }
    // positional GEMM (K=64, 36 used)
    #pragma unroll
    for (int ks = 0; ks < 2; ++ks) {
        f16x8 Bv[NT];
        #pragma unroll
        for (int nt = 0; nt < NT; ++nt) {
            int g = FAT ? (nt >> 2) : gO;
            int pix = (nt & 3) * 16 + colp;
            Bv[nt] = *(const f16x8*)&posim[g * 64 * PIP + pix * PIP + ks * 32 + kg * 8];
        }
        #pragma unroll
        for (int e = 0; e < NE; ++e) {
            int ao = (e * CO + co0 + colp) * 64 + ks * 32 + kg * 8;
            f16x8 Ah = *(const f16x8*)(WpH + ao);
            f16x8 Al = *(const f16x8*)(WpL + ao);
            __builtin_amdgcn_s_setprio(1);
            #pragma unroll
            for (int nt = 0; nt < NT; ++nt) {
                acc[e][nt] = __builtin_amdgcn_mfma_f32_16x16x32_f16(Ah, Bv[nt], acc[e][nt], 0, 0, 0);
                acc[e][nt] = __builtin_amdgcn_mfma_f32_16x16x32_f16(Al, Bv[nt], acc[e][nt], 0, 0, 0);
            }
            __builtin_amdgcn_s_setprio(0);
        }
    }

    // bias + relu + gated combine -> comb (fp16)
    float sg0[NE], sg1[NE];
    #pragma unroll
    for (int e = 0; e < NE; ++e) {
        float gv = gate[e];
        sg0[e] = scores[bp0 * NE + e] * gv;
        sg1[e] = scores[bp1 * NE + e] * gv;
    }
    float ebv[NE][4];
    #pragma unroll
    for (int e = 0; e < NE; ++e)
        #pragma unroll
        for (int r = 0; r < 4; ++r) ebv[e][r] = eb[e * CO + co0 + kg * 4 + r];
    #pragma unroll
    for (int nt = 0; nt < NT; ++nt) {
        const int g = FAT ? (nt >> 2) : gO;
        int pix = (nt & 3) * 16 + colp;
        u16 hv[4];
        #pragma unroll
        for (int r = 0; r < 4; ++r) {
            float cv = 0.f;
            #pragma unroll
            for (int e = 0; e < NE; ++e) {
                float s = g ? sg1[e] : sg0[e];
                cv += s * fmaxf(acc[e][nt][r] + ebv[e][r], 0.f);
            }
            hv[r] = f16bits(cv);
        }
        uint2 q;
        q.x = (u32)hv[0] | ((u32)hv[1] << 16);
        q.y = (u32)hv[2] | ((u32)hv[3] << 16);
        *(uint2*)&comb[g * 64 * CP + pix * CP + co0 + kg * 4] = q;
    }
    __syncthreads();

    // fin GEMM: wave's 16 o-rows x both patches
    const int o0 = co0;
    f32x4 accF[NT];
    #pragma unroll
    for (int nt = 0; nt < NT; ++nt) accF[nt] = (f32x4){0.f, 0.f, 0.f, 0.f};
    #pragma unroll
    for (int ks = 0; ks < CO / 32; ++ks) {
        int ao = (o0 + colp) * CO + ks * 32 + kg * 8;
        f16x8 ah = *(const f16x8*)(fWH + ao);
        f16x8 al = *(const f16x8*)(fWL + ao);
        __builtin_amdgcn_s_setprio(1);
        #pragma unroll
        for (int nt = 0; nt < NT; ++nt) {
            int g = FAT ? (nt >> 2) : gO;
            int pix = (nt & 3) * 16 + colp;
            f16x8 bv = *(const f16x8*)&comb[g * 64 * CP + pix * CP + ks * 32 + kg * 8];
            accF[nt] = __builtin_amdgcn_mfma_f32_16x16x32_f16(ah, bv, accF[nt], 0, 0, 0);
            accF[nt] = __builtin_amdgcn_mfma_f32_16x16x32_f16(al, bv, accF[nt], 0, 0, 0);
        }
        __builtin_amdgcn_s_setprio(0);
    }
    float fbv[4];
    #pragma unroll
    for (int r = 0; r < 4; ++r) fbv[r] = fb[o0 + kg * 4 + r];
    #pragma unroll
    for (int nt = 0; nt < NT; ++nt) {
        const int g = FAT ? (nt >> 2) : gO;
        int pix = (nt & 3) * 16 + colp;
        int bb = g ? b1 : b0, py = g ? py1 : py0, px = g ? px1 : px0;
        int gy = py * 8 + (pix >> 3) + 4, gx = px * 8 + (pix & 7) + 4;
        #pragma unroll
        for (int r = 0; r < 4; ++r) {
            int o = o0 + kg * 4 + r;
            Xn[(((size_t)bb * CO + o) * Hout + gy) * Wout + gx] = accF[nt][r] + fbv[r];
        }
    }
}

// ---------------- final linear ----------------
__global__ __launch_bounds__(256) void linear_kernel(
    const float* __restrict__ Xf, const float* __restrict__ lw, const float* __restrict__ lb,
    float* __restrict__ out)
{
    const int b = blockIdx.x / 10, o = blockIdx.x % 10;
    const int feat = 128 * 96 * 96;
    const float4* xa = (const float4*)(Xf + (size_t)b * feat);
    const float4* wa = (const float4*)(lw + (size_t)o * feat);
    float acc = 0.f;
    for (int i = threadIdx.x; i < feat / 4; i += 256) {
        float4 xv = xa[i], wv = wa[i];
        acc += xv.x * wv.x + xv.y * wv.y + xv.z * wv.z + xv.w * wv.w;
    }
    for (int m = 32; m; m >>= 1) acc += __shfl_xor(acc, m);
    __shared__ float sm[4];
    if ((threadIdx.x & 63) == 0) sm[threadIdx.x >> 6] = acc;
    __syncthreads();
    if (threadIdx.x == 0) out[blockIdx.x] = sm[0] + sm[1] + sm[2] + sm[3] + lb[o];
}

// ---------------- host driver ----------------
template<int CIN, int CINp, int CO>
static void run_layer(const float* Xin, int H, int nP, const float* const* Lw,
                      const float* rw, const float* rb,
                      u16* WmH, u16* WmL, u16* WpH, u16* WpL, u16* fWH, u16* fWL,
                      float* scores, float* gate, float* Xn, hipStream_t stream)
{
    const int W = H;
    const int BP = NB * nP * nP;
    const float* pw = Lw[0]; const float* pb = Lw[1];
    const float* ew = Lw[2]; const float* ebias = Lw[3];
    const float* fw = Lw[4]; const float* fb = Lw[5];

    repack_all_kernel<<<1024, 256, 0, stream>>>(ew, fw, WmH, WmL, WpH, WpL, fWH, fWL,
                                                CO, CIN, CINp, CIN + 4);
    router_kernel<CIN, CIN + 4><<<BP / 4, 256, 0, stream>>>(Xin, pw, pb, rw, rb, scores, H, W, nP);
    gate_kernel<<<1, 256, 0, stream>>>(scores, BP, gate);
    border_kernel<<<2048, 256, 0, stream>>>(Xn, fb, CO, H, W);
    expert_fused_kernel<CIN, CINp, CO><<<BP / 2, 512, 0, stream>>>(
        Xin, WmH, WmL, WpH, WpL, fWH, fWL, ebias, fb, scores, gate, Xn, H, W, nP);
}

extern "C" void kernel_launch(void* const* d_in, const int* in_sizes, int n_in,
                              void* d_out, int out_size, void* d_ws, size_t ws_size,
                              hipStream_t stream)
{
    const float* X0 = (const float*)d_in[0];
    const float* L[4][6];
    for (int l = 0; l < 4; ++l)
        for (int k = 0; k < 6; ++k) L[l][k] = (const float*)d_in[1 + l * 6 + k];
    const float* rw = (const float*)d_in[25];
    const float* rb = (const float*)d_in[26];
    const float* lw = (const float*)d_in[27];
    const float* lb = (const float*)d_in[28];

    // workspace (~141.5 MB): ping-pong X buffers + fp16 weight planes
    char* ws = (char*)d_ws;
    const size_t XA_B = 63438848;    // 16*128*88*88*4 (L3 out, max for A)
    const size_t XB_B = 75497472;    // 16*128*96*96*4 (L4 out, max for B)
    const size_t WM_B = 1179648;     // 9*512*128*2
    const size_t WP_B = 65536;       // 512*64*2
    const size_t FW_B = 32768;       // 128*128*2
    float* XA = (float*)(ws);
    float* XB = (float*)(ws + XA_B);
    u16* WmH = (u16*)(ws + XA_B + XB_B);
    u16* WmL = (u16*)(ws + XA_B + XB_B + WM_B);
    u16* WpH = (u16*)(ws + XA_B + XB_B + 2 * WM_B);
    u16* WpL = (u16*)(ws + XA_B + XB_B + 2 * WM_B + WP_B);
    u16* fWH = (u16*)(ws + XA_B + XB_B + 2 * WM_B + 2 * WP_B);
    u16* fWL = (u16*)(ws + XA_B + XB_B + 2 * WM_B + 2 * WP_B + FW_B);
    float* scores = (float*)(ws + XA_B + XB_B + 2 * WM_B + 2 * WP_B + 2 * FW_B);
    float* gate = scores + 1936 * 4;

    // layer l: X (NB,CIN,H,H) -> Xn (NB,CO,H+8,H+8), ping-pong A/B
    run_layer<3,   32,  64>(X0, 64,  8, L[0], rw, rb, WmH, WmL, WpH, WpL, fWH, fWL, scores, gate, XA, stream);
    run_layer<64,  64,  64>(XA, 72,  9, L[1], rw, rb, WmH, WmL, WpH, WpL, fWH, fWL, scores, gate, XB, stream);
    run_layer<64,  64, 128>(XB, 80, 10, L[2], rw, rb, WmH, WmL, WpH, WpL, fWH, fWL, scores, gate, XA, stream);
    run_layer<128, 128, 128>(XA, 88, 11, L[3], rw, rb, WmH, WmL, WpH, WpL, fWH, fWL, scores, gate, XB, stream);

    linear_kernel<<<160, 256, 0, stream>>>(XB, lw, lb, (float*)d_out);
}

// Round 9
// 1064.716 us; speedup vs baseline: 8.9251x; 1.2633x over previous
//
#include <hip/hip_runtime.h>
#include <math.h>

#define NB 16
#define NE 4
#define THRESH 0.2f
#define LIN_NS 64

typedef __attribute__((ext_vector_type(8))) _Float16 f16x8;
typedef __attribute__((ext_vector_type(4))) float f32x4;
typedef unsigned short u16;
typedef unsigned int u32;

__device__ inline u16 f16bits(float v) { _Float16 h = (_Float16)v; return __builtin_bit_cast(u16, h); }
__device__ inline float f16lo(float v) { _Float16 h = (_Float16)v; return v - (float)h; }

// ---------------- repack: expert weights (main+pos) and fin weights to fp16 hi/lo ----------------
// WmH/WmL: [ij][m=e*CO+co][CINp]   WpH/WpL: [m][64] (kp=pc*9+ij, <36 used)   fWH/fWL: [o][CO]
__global__ void repack_all_kernel(const float* __restrict__ ew, const float* __restrict__ fw,
    u16* __restrict__ WmH, u16* __restrict__ WmL, u16* __restrict__ WpH, u16* __restrict__ WpL,
    u16* __restrict__ fWH, u16* __restrict__ fWL, int CO, int CIN, int CINp, int C) {
    const int M = NE * CO;
    const int n1 = 9 * M * CINp, n2 = M * 64, n3 = CO * CO;
    const int n = n1 + n2 + n3;
    for (int i = blockIdx.x * blockDim.x + threadIdx.x; i < n; i += gridDim.x * blockDim.x) {
        if (i < n1) {
            int k = i % CINp; int t = i / CINp; int m = t % M; int ij = t / M;
            float v = (k < CIN) ? ew[(m * C + k) * 9 + ij] : 0.f;
            WmH[i] = f16bits(v); WmL[i] = f16bits(f16lo(v));
        } else if (i < n1 + n2) {
            int j = i - n1; int kp = j & 63; int m = j >> 6;
            float v = 0.f;
            if (kp < 36) { int pc = kp / 9, ij = kp % 9; v = ew[(m * C + CIN + pc) * 9 + ij]; }
            WpH[j] = f16bits(v); WpL[j] = f16bits(f16lo(v));
        } else {
            int j = i - n1 - n2;
            float v = fw[j];
            fWH[j] = f16bits(v); fWL[j] = f16bits(f16lo(v));
        }
    }
}

// ---------------- router: pooled conv -> softmax scores (verified) ----------------
template<int CIN, int C>
__global__ __launch_bounds__(256) void router_kernel(
    const float* __restrict__ X, const float* __restrict__ pw, const float* __restrict__ pb,
    const float* __restrict__ rw, const float* __restrict__ rb,
    float* __restrict__ scores, int H, int W, int nP)
{
    __shared__ float S[4][C * 9 + 8];
    const int wv = threadIdx.x >> 6;
    const int lane = threadIdx.x & 63;
    const int bp = blockIdx.x * 4 + wv;
    const int P = nP * nP;
    const int b = bp / P, pi = bp % P;
    const int py = pi / nP, px = pi % nP;
    const int h = lane >> 3, w = lane & 7;
    const int gy = py * 8 + h, gx = px * 8 + w;
    float* Sw = S[wv];
    for (int c = 0; c < C; ++c) {
        float v;
        if (c < CIN) {
            v = X[(((size_t)b * CIN + c) * H + gy) * W + gx];
        } else {
            float t = (c == CIN || c == CIN + 2) ? gx * (1.f / (W - 1)) : gy * (1.f / (H - 1));
            v = (c >= CIN + 2) ? sinf(3.14159265358979323846f * t) : t;
        }
        float r = v;
        r += __shfl_xor(r, 1); r += __shfl_xor(r, 2); r += __shfl_xor(r, 4);
        float cc = v;
        cc += __shfl_xor(cc, 8); cc += __shfl_xor(cc, 16); cc += __shfl_xor(cc, 32);
        float T = r;
        T += __shfl_xor(T, 8); T += __shfl_xor(T, 16); T += __shfl_xor(T, 32);
        float R0 = __shfl(r, 0), R7 = __shfl(r, 56);
        float C0 = __shfl(cc, 0), C7 = __shfl(cc, 7);
        float x00 = __shfl(v, 0), x07 = __shfl(v, 7);
        float x70 = __shfl(v, 56), x77 = __shfl(v, 63);
        if (lane < 9) {
            int i = lane / 3, j = lane % 3;
            float s = T;
            if (i == 0) s -= R7; else if (i == 2) s -= R0;
            if (j == 0) s -= C7; else if (j == 2) s -= C0;
            if (i == 0 && j == 0) s += x77;
            else if (i == 0 && j == 2) s += x70;
            else if (i == 2 && j == 0) s += x07;
            else if (i == 2 && j == 2) s += x00;
            Sw[c * 9 + lane] = s;
        }
    }
    __syncthreads();
    if (lane < 8) {
        const int o = lane;
        float acc = 0.f;
        for (int c = 0; c < C; ++c) {
            #pragma unroll
            for (int ij = 0; ij < 9; ++ij)
                acc += pw[(o * C + c) * 9 + ij] * Sw[c * 9 + ij];
        }
        Sw[C * 9 + o] = acc * (1.f / 64.f) + pb[o];
    }
    __syncthreads();
    if (lane == 0) {
        float lg[NE];
        float m = -1e30f;
        #pragma unroll
        for (int e = 0; e < NE; ++e) {
            float a = rb[e];
            #pragma unroll
            for (int o = 0; o < 8; ++o) a += Sw[C * 9 + o] * rw[e * 8 + o];
            lg[e] = a;
            m = fmaxf(m, a);
        }
        float ssum = 0.f;
        #pragma unroll
        for (int e = 0; e < NE; ++e) { lg[e] = __expf(lg[e] - m); ssum += lg[e]; }
        float inv = 1.f / ssum;
        #pragma unroll
        for (int e = 0; e < NE; ++e) scores[bp * NE + e] = lg[e] * inv;
    }
}

// ---------------- gate ----------------
__global__ __launch_bounds__(256) void gate_kernel(const float* __restrict__ scores, int BP,
                                                   float* __restrict__ gate)
{
    __shared__ float sm[4][NE];
    float m[NE] = {-1e30f, -1e30f, -1e30f, -1e30f};
    for (int i = threadIdx.x; i < BP; i += 256) {
        #pragma unroll
        for (int e = 0; e < NE; ++e) m[e] = fmaxf(m[e], scores[i * NE + e]);
    }
    #pragma unroll
    for (int e = 0; e < NE; ++e) {
        float v = m[e];
        for (int o = 32; o; o >>= 1) v = fmaxf(v, __shfl_xor(v, o));
        m[e] = v;
    }
    int wv = threadIdx.x >> 6, lane = threadIdx.x & 63;
    if (lane == 0) {
        #pragma unroll
        for (int e = 0; e < NE; ++e) sm[wv][e] = m[e];
    }
    __syncthreads();
    if (threadIdx.x == 0) {
        #pragma unroll
        for (int e = 0; e < NE; ++e) {
            float mx = fmaxf(fmaxf(sm[0][e], sm[1][e]), fmaxf(sm[2][e], sm[3][e]));
            gate[e] = (mx > THRESH) ? 1.f : 0.f;
        }
    }
}

// ---------------- border: Xn border pixels = fin bias ----------------
__global__ __launch_bounds__(256) void border_kernel(float* __restrict__ Xn,
                                                     const float* __restrict__ fb,
                                                     int CO, int H, int W)
{
    const int Hout = H + 8, Wout = W + 8;
    const int nb = 16 * H + 64;
    const long total = (long)NB * CO * nb;
    for (long i = (long)blockIdx.x * blockDim.x + threadIdx.x; i < total;
         i += (long)gridDim.x * blockDim.x) {
        int j = (int)(i % nb); long t = i / nb; int o = (int)(t % CO); int b = (int)(t / CO);
        int y, x;
        if (j < 4 * Wout)       { y = j / Wout;             x = j % Wout; }
        else if (j < 8 * Wout)  { int j2 = j - 4 * Wout; y = H + 4 + j2 / Wout; x = j2 % Wout; }
        else                    { int j3 = j - 8 * Wout; y = 4 + j3 / 8;
                                  int c8 = j3 % 8; x = (c8 < 4) ? c8 : W + 4 + (c8 - 4); }
        Xn[(((size_t)b * CO + o) * Hout + y) * Wout + x] = fb[o];
    }
}

// ---------------- fused expert + fin, 2 patches per 512-thread block (verified R8) ----------------
template<int CIN, int CINp, int CO>
__global__ __launch_bounds__(512, 2) void expert_fused_kernel(
    const float* __restrict__ X,
    const u16* __restrict__ WmH, const u16* __restrict__ WmL,
    const u16* __restrict__ WpH, const u16* __restrict__ WpL,
    const u16* __restrict__ fWH, const u16* __restrict__ fWL,
    const float* __restrict__ eb, const float* __restrict__ fb,
    const float* __restrict__ scores, const float* __restrict__ gate,
    float* __restrict__ Xn, int H, int W, int nP)
{
    constexpr int M = NE * CO;
    constexpr int KSM = CINp / 32;
    constexpr int SP = CINp + 8;
    constexpr int PIP = 72;
    constexpr int CP = CO + 8;
    constexpr bool FAT = (CO == 128);
    constexpr int NT = FAT ? 8 : 4;

    __shared__ __align__(16) u16 pat[2 * 100 * SP];
    __shared__ __align__(16) u16 posim[2 * 64 * PIP];
    __shared__ __align__(16) u16 comb[2 * 64 * CP];
    __shared__ float pospix[2][4][64];

    const int P = nP * nP;
    const int bp0 = blockIdx.x * 2, bp1 = bp0 + 1;
    const int b0 = bp0 / P, pi0 = bp0 % P, py0 = pi0 / nP, px0 = pi0 % nP;
    const int b1 = bp1 / P, pi1 = bp1 % P, py1 = pi1 / nP, px1 = pi1 % nP;
    const int tid = threadIdx.x;
    const int Hout = H + 8, Wout = W + 8;

    for (int i = tid; i < 100 * SP; i += 512) ((u32*)pat)[i] = 0;
    {
        int g = tid >> 8, r = tid & 255, pc = r >> 6, p = r & 63;
        int gy = (g ? py1 : py0) * 8 + (p >> 3), gx = (g ? px1 : px0) * 8 + (p & 7);
        float t = (pc == 0 || pc == 2) ? gx * (1.f / (W - 1)) : gy * (1.f / (H - 1));
        pospix[g][pc][p] = (pc >= 2) ? sinf(3.14159265358979323846f * t) : t;
    }
    __syncthreads();
    for (int i = tid; i < 2 * CIN * 16; i += 512) {
        int g = i / (CIN * 16), j = i % (CIN * 16);
        int c = j >> 4, q = j & 15, h = q >> 1, w4 = (q & 1) * 4;
        int bb = g ? b1 : b0, py = g ? py1 : py0, px = g ? px1 : px0;
        const float4 v = *(const float4*)&X[(((size_t)bb * CIN + c) * H + py * 8 + h) * W + px * 8 + w4];
        int base = g * 100 * SP + c;
        pat[base + ((h + 1) * 10 + (w4 + 1)) * SP] = f16bits(v.x);
        pat[base + ((h + 1) * 10 + (w4 + 2)) * SP] = f16bits(v.y);
        pat[base + ((h + 1) * 10 + (w4 + 3)) * SP] = f16bits(v.z);
        pat[base + ((h + 1) * 10 + (w4 + 4)) * SP] = f16bits(v.w);
    }
    for (int i = tid; i < 2 * 64 * 64; i += 512) {
        int g = i >> 12, r = i & 4095, pix = r >> 6, kp = r & 63;
        float v = 0.f;
        if (kp < 36) {
            int pc = kp / 9, ij = kp % 9;
            int hh = (pix >> 3) + ij / 3 - 1, ww = (pix & 7) + ij % 3 - 1;
            if (hh >= 0 && hh < 8 && ww >= 0 && ww < 8) v = pospix[g][pc][hh * 8 + ww];
        }
        posim[g * 64 * PIP + pix * PIP + kp] = f16bits(v);
    }
    __syncthreads();

    const int lane = tid & 63, wv = tid >> 6;
    const int colp = lane & 15, kg = lane >> 4;
    const int cot = FAT ? wv : (wv & 3);
    const int gO = FAT ? 0 : (wv >> 2);
    const int co0 = cot * 16;

    int prow[NT];
    #pragma unroll
    for (int nt = 0; nt < NT; ++nt) {
        int g = FAT ? (nt >> 2) : gO;
        int pix = (nt & 3) * 16 + colp;
        prow[nt] = g * 100 * SP + ((pix >> 3) * 10 + (pix & 7)) * SP;
    }
    int aoff[NE];
    #pragma unroll
    for (int e = 0; e < NE; ++e)
        aoff[e] = (e * CO + co0 + colp) * CINp + kg * 8;

    f32x4 acc[NE][NT];
    #pragma unroll
    for (int e = 0; e < NE; ++e)
        #pragma unroll
        for (int nt = 0; nt < NT; ++nt) acc[e][nt] = (f32x4){0.f, 0.f, 0.f, 0.f};

    for (int ij = 0; ij < 9; ++ij) {
        const int tap = (ij / 3) * 10 + (ij % 3);
        const int wb = ij * M * CINp;
        #pragma unroll
        for (int ks = 0; ks < KSM; ++ks) {
            f16x8 Bv[NT];
            #pragma unroll
            for (int nt = 0; nt < NT; ++nt)
                Bv[nt] = *(const f16x8*)&pat[prow[nt] + tap * SP + ks * 32 + kg * 8];
            #pragma unroll
            for (int e = 0; e < NE; ++e) {
                f16x8 Ah = *(const f16x8*)(WmH + wb + aoff[e] + ks * 32);
                f16x8 Al = *(const f16x8*)(WmL + wb + aoff[e] + ks * 32);
                __builtin_amdgcn_s_setprio(1);
                #pragma unroll
                for (int nt = 0; nt < NT; ++nt) {
                    acc[e][nt] = __builtin_amdgcn_mfma_f32_16x16x32_f16(Ah, Bv[nt], acc[e][nt], 0, 0, 0);
                    acc[e][nt] = __builtin_amdgcn_mfma_f32_16x16x32_f16(Al, Bv[nt], acc[e][nt], 0, 0, 0);
                }
                __builtin_amdgcn_s_setprio(0);
            }
        }
    }
    #pragma unroll
    for (int ks = 0; ks < 2; ++ks) {
        f16x8 Bv[NT];
        #pragma unroll
        for (int nt = 0; nt < NT; ++nt) {
            int g = FAT ? (nt >> 2) : gO;
            int pix = (nt & 3) * 16 + colp;
            Bv[nt] = *(const f16x8*)&posim[g * 64 * PIP + pix * PIP + ks * 32 + kg * 8];
        }
        #pragma unroll
        for (int e = 0; e < NE; ++e) {
            int ao = (e * CO + co0 + colp) * 64 + ks * 32 + kg * 8;
            f16x8 Ah = *(const f16x8*)(WpH + ao);
            f16x8 Al = *(const f16x8*)(WpL + ao);
            __builtin_amdgcn_s_setprio(1);
            #pragma unroll
            for (int nt = 0; nt < NT; ++nt) {
                acc[e][nt] = __builtin_amdgcn_mfma_f32_16x16x32_f16(Ah, Bv[nt], acc[e][nt], 0, 0, 0);
                acc[e][nt] = __builtin_amdgcn_mfma_f32_16x16x32_f16(Al, Bv[nt], acc[e][nt], 0, 0, 0);
            }
            __builtin_amdgcn_s_setprio(0);
        }
    }

    float sg0[NE], sg1[NE];
    #pragma unroll
    for (int e = 0; e < NE; ++e) {
        float gv = gate[e];
        sg0[e] = scores[bp0 * NE + e] * gv;
        sg1[e] = scores[bp1 * NE + e] * gv;
    }
    float ebv[NE][4];
    #pragma unroll
    for (int e = 0; e < NE; ++e)
        #pragma unroll
        for (int r = 0; r < 4; ++r) ebv[e][r] = eb[e * CO + co0 + kg * 4 + r];
    #pragma unroll
    for (int nt = 0; nt < NT; ++nt) {
        const int g = FAT ? (nt >> 2) : gO;
        int pix = (nt & 3) * 16 + colp;
        u16 hv[4];
        #pragma unroll
        for (int r = 0; r < 4; ++r) {
            float cv = 0.f;
            #pragma unroll
            for (int e = 0; e < NE; ++e) {
                float s = g ? sg1[e] : sg0[e];
                cv += s * fmaxf(acc[e][nt][r] + ebv[e][r], 0.f);
            }
            hv[r] = f16bits(cv);
        }
        uint2 q;
        q.x = (u32)hv[0] | ((u32)hv[1] << 16);
        q.y = (u32)hv[2] | ((u32)hv[3] << 16);
        *(uint2*)&comb[g * 64 * CP + pix * CP + co0 + kg * 4] = q;
    }
    __syncthreads();

    const int o0 = co0;
    f32x4 accF[NT];
    #pragma unroll
    for (int nt = 0; nt < NT; ++nt) accF[nt] = (f32x4){0.f, 0.f, 0.f, 0.f};
    #pragma unroll
    for (int ks = 0; ks < CO / 32; ++ks) {
        int ao = (o0 + colp) * CO + ks * 32 + kg * 8;
        f16x8 ah = *(const f16x8*)(fWH + ao);
        f16x8 al = *(const f16x8*)(fWL + ao);
        __builtin_amdgcn_s_setprio(1);
        #pragma unroll
        for (int nt = 0; nt < NT; ++nt) {
            int g = FAT ? (nt >> 2) : gO;
            int pix = (nt & 3) * 16 + colp;
            f16x8 bv = *(const f16x8*)&comb[g * 64 * CP + pix * CP + ks * 32 + kg * 8];
            accF[nt] = __builtin_amdgcn_mfma_f32_16x16x32_f16(ah, bv, accF[nt], 0, 0, 0);
            accF[nt] = __builtin_amdgcn_mfma_f32_16x16x32_f16(al, bv, accF[nt], 0, 0, 0);
        }
        __builtin_amdgcn_s_setprio(0);
    }
    float fbv[4];
    #pragma unroll
    for (int r = 0; r < 4; ++r) fbv[r] = fb[o0 + kg * 4 + r];
    #pragma unroll
    for (int nt = 0; nt < NT; ++nt) {
        const int g = FAT ? (nt >> 2) : gO;
        int pix = (nt & 3) * 16 + colp;
        int bb = g ? b1 : b0, py = g ? py1 : py0, px = g ? px1 : px0;
        int gy = py * 8 + (pix >> 3) + 4, gx = px * 8 + (pix & 7) + 4;
        #pragma unroll
        for (int r = 0; r < 4; ++r) {
            int o = o0 + kg * 4 + r;
            Xn[(((size_t)bb * CO + o) * Hout + gy) * Wout + gx] = accF[nt][r] + fbv[r];
        }
    }
}

// ---------------- final linear: stage 1 — per (b, feat-split) partial dots ----------------
// grid = 16*LIN_NS blocks; each block reads a 72KB X-chunk ONCE for all 10 outputs.
// (R8: 160-block monolith = 490us at 7% occupancy, 2.4% VALU; latency-bound.)
__global__ __launch_bounds__(256) void linear_part_kernel(
    const float* __restrict__ Xf, const float* __restrict__ lw, float* __restrict__ part)
{
    const int feat = 128 * 96 * 96;
    const int CH = feat / LIN_NS;          // 18432
    const int b = blockIdx.x / LIN_NS, s = blockIdx.x % LIN_NS;
    const float4* xa = (const float4*)(Xf + (size_t)b * feat + (size_t)s * CH);
    const float* wbase = lw + (size_t)s * CH;
    float acc[10];
    #pragma unroll
    for (int o = 0; o < 10; ++o) acc[o] = 0.f;
    const int n4 = CH / 4;                 // 4608
    for (int i = threadIdx.x; i < n4; i += 256) {
        float4 xv = xa[i];
        #pragma unroll
        for (int o = 0; o < 10; ++o) {
            float4 wv = *(const float4*)(wbase + (size_t)o * feat + i * 4);
            acc[o] += xv.x * wv.x + xv.y * wv.y + xv.z * wv.z + xv.w * wv.w;
        }
    }
    #pragma unroll
    for (int o = 0; o < 10; ++o)
        for (int m = 32; m; m >>= 1) acc[o] += __shfl_xor(acc[o], m);
    __shared__ float sm[4][10];
    int wv = threadIdx.x >> 6, lane = threadIdx.x & 63;
    if (lane == 0) {
        #pragma unroll
        for (int o = 0; o < 10; ++o) sm[wv][o] = acc[o];
    }
    __syncthreads();
    if (threadIdx.x < 10)
        part[(b * LIN_NS + s) * 10 + threadIdx.x] =
            sm[0][threadIdx.x] + sm[1][threadIdx.x] + sm[2][threadIdx.x] + sm[3][threadIdx.x];
}

// ---------------- final linear: stage 2 — reduce splits + bias (deterministic) ----------------
__global__ __launch_bounds__(256) void linear_reduce_kernel(
    const float* __restrict__ part, const float* __restrict__ lb, float* __restrict__ out)
{
    int i = threadIdx.x;
    if (i < 160) {
        int b = i / 10, o = i % 10;
        float a = lb[o];
        for (int s = 0; s < LIN_NS; ++s) a += part[(b * LIN_NS + s) * 10 + o];
        out[i] = a;
    }
}

// ---------------- host driver ----------------
template<int CIN, int CINp, int CO>
static void run_layer(const float* Xin, int H, int nP, const float* const* Lw,
                      const float* rw, const float* rb,
                      u16* WmH, u16* WmL, u16* WpH, u16* WpL, u16* fWH, u16* fWL,
                      float* scores, float* gate, float* Xn, hipStream_t stream)
{
    const int W = H;
    const int BP = NB * nP * nP;
    const float* pw = Lw[0]; const float* pb = Lw[1];
    const float* ew = Lw[2]; const float* ebias = Lw[3];
    const float* fw = Lw[4]; const float* fb = Lw[5];

    repack_all_kernel<<<1024, 256, 0, stream>>>(ew, fw, WmH, WmL, WpH, WpL, fWH, fWL,
                                                CO, CIN, CINp, CIN + 4);
    router_kernel<CIN, CIN + 4><<<BP / 4, 256, 0, stream>>>(Xin, pw, pb, rw, rb, scores, H, W, nP);
    gate_kernel<<<1, 256, 0, stream>>>(scores, BP, gate);
    border_kernel<<<2048, 256, 0, stream>>>(Xn, fb, CO, H, W);
    expert_fused_kernel<CIN, CINp, CO><<<BP / 2, 512, 0, stream>>>(
        Xin, WmH, WmL, WpH, WpL, fWH, fWL, ebias, fb, scores, gate, Xn, H, W, nP);
}

extern "C" void kernel_launch(void* const* d_in, const int* in_sizes, int n_in,
                              void* d_out, int out_size, void* d_ws, size_t ws_size,
                              hipStream_t stream)
{
    const float* X0 = (const float*)d_in[0];
    const float* L[4][6];
    for (int l = 0; l < 4; ++l)
        for (int k = 0; k < 6; ++k) L[l][k] = (const float*)d_in[1 + l * 6 + k];
    const float* rw = (const float*)d_in[25];
    const float* rb = (const float*)d_in[26];
    const float* lw = (const float*)d_in[27];
    const float* lb = (const float*)d_in[28];

    // workspace (~142 MB): ping-pong X buffers + fp16 weight planes + linear partials
    char* ws = (char*)d_ws;
    const size_t XA_B = 63438848;    // 16*128*88*88*4 (L3 out, max for A)
    const size_t XB_B = 75497472;    // 16*128*96*96*4 (L4 out, max for B)
    const size_t WM_B = 1179648;     // 9*512*128*2
    const size_t WP_B = 65536;       // 512*64*2
    const size_t FW_B = 32768;       // 128*128*2
    float* XA = (float*)(ws);
    float* XB = (float*)(ws + XA_B);
    u16* WmH = (u16*)(ws + XA_B + XB_B);
    u16* WmL = (u16*)(ws + XA_B + XB_B + WM_B);
    u16* WpH = (u16*)(ws + XA_B + XB_B + 2 * WM_B);
    u16* WpL = (u16*)(ws + XA_B + XB_B + 2 * WM_B + WP_B);
    u16* fWH = (u16*)(ws + XA_B + XB_B + 2 * WM_B + 2 * WP_B);
    u16* fWL = (u16*)(ws + XA_B + XB_B + 2 * WM_B + 2 * WP_B + FW_B);
    float* scores = (float*)(ws + XA_B + XB_B + 2 * WM_B + 2 * WP_B + 2 * FW_B);
    float* gate = scores + 1936 * 4;
    float* lpart = gate + 64;        // 16*LIN_NS*10 floats

    // layer l: X (NB,CIN,H,H) -> Xn (NB,CO,H+8,H+8), ping-pong A/B
    run_layer<3,   32,  64>(X0, 64,  8, L[0], rw, rb, WmH, WmL, WpH, WpL, fWH, fWL, scores, gate, XA, stream);
    run_layer<64,  64,  64>(XA, 72,  9, L[1], rw, rb, WmH, WmL, WpH, WpL, fWH, fWL, scores, gate, XB, stream);
    run_layer<64,  64, 128>(XB, 80, 10, L[2], rw, rb, WmH, WmL, WpH, WpL, fWH, fWL, scores, gate, XA, stream);
    run_layer<128, 128, 128>(XA, 88, 11, L[3], rw, rb, WmH, WmL, WpH, WpL, fWH, fWL, scores, gate, XB, stream);

    linear_part_kernel<<<16 * LIN_NS, 256, 0, stream>>>(XB, lw, lpart);
    linear_reduce_kernel<<<1, 256, 0, stream>>>(lpart, lb, (float*)d_out);
}